// Round 2
// baseline (873.355 us; speedup 1.0000x reference)
//
#include <hip/hip_runtime.h>
#include <math.h>

constexpr int kBn    = 4;
constexpr int kText  = 64;
constexpr int kImg   = 256;
constexpr int kDim   = 1024;
constexpr int kHeads = 16;
constexpr int kHd    = 64;
constexpr int kNp    = 256;    // patches
constexpr int kTok   = 321;    // 64 text + 1 cls + 256 img
constexpr int kVocab = 50000;
constexpr int kTdim  = 256;
constexpr int kMlp   = 4096;
constexpr int kScLd  = 328;    // score row stride (321 padded to mult of 8)
constexpr float kEps = 1e-5f;

typedef __attribute__((ext_vector_type(8))) short short8;
typedef __attribute__((ext_vector_type(4))) float f32x4;

// RNE float -> bf16 bits
__device__ __forceinline__ short f2bf(float x) {
  unsigned u = __builtin_bit_cast(unsigned, x);
  unsigned r = (u + 0x7FFFu + ((u >> 16) & 1u)) >> 16;
  return (short)r;
}

// =================================================================== MFMA GEMM
// C[m][n] = alpha * sum_k A[m][k] * B[n][k]   (A,B bf16 in memory, fp32 accum)
// EPI: 0 none | 1 +bias[n] | 3 gelu | 4 +E[m][n] | 5 gated residual
// PART: split-K partial, raw fp32 write to C + split*partStride.
// OUTBF: store bf16 (C reinterpreted as short*).
struct GemmM {
  const short* A; const short* B; float* C; const float* E;
  int M, N, K, lda, ldb, ldc;
  long sA0, sA1, sB0, sB1, sC0, sC1;
  int innerB, ldE, rowsPB;
  float alpha;
  int nSplit, splitLen;
  long partStride;
};

__device__ __forceinline__ float epi_apply(int EPI, const GemmM& p, const float* E,
                                           long co, int gm, int gn, float v) {
  if (EPI == 1) v += E[gn];
  else if (EPI == 3) v = 0.5f*v*(1.f + erff(v*0.70710678118654752f));
  else if (EPI == 4) v += E[(long)gm*p.ldE + gn];
  else if (EPI == 5) v = p.C[co] + E[(long)(gm / p.rowsPB)*p.ldE + gn] * v;
  return v;
}

// ---------------------------------------------------- 64x64 tile (attention)
template<int EPI, bool PART, bool OUTBF>
__global__ __launch_bounds__(256) void gemm_mfma(GemmM p) {
  int bz = blockIdx.z;
  int split = 0;
  if (PART) { split = bz % p.nSplit; bz /= p.nSplit; }
  int b1 = bz % p.innerB, b0 = bz / p.innerB;
  const short* A = p.A + b0*p.sA0 + b1*p.sA1;
  const short* B = p.B + b0*p.sB0 + b1*p.sB1;
  long cbase = b0*p.sC0 + b1*p.sC1 + (PART ? (long)split * p.partStride : 0);
  const float* E = p.E;

  int kBeg = PART ? split * p.splitLen : 0;
  int kEnd = PART ? min(p.K, kBeg + p.splitLen) : p.K;

  __shared__ short As[64*72];   // rows = m (64), cols = k (64) + pad 8
  __shared__ short Bs[64*72];   // rows = n (64), cols = k (64) + pad 8

  int tid  = threadIdx.x;
  int lane = tid & 63, widx = tid >> 6;
  int quad = lane >> 4, ln = lane & 15;
  int wm = (widx >> 1) * 32, wn = (widx & 1) * 32;
  int n0 = blockIdx.x * 64, m0 = blockIdx.y * 64;

  f32x4 zero = {0.f, 0.f, 0.f, 0.f};
  f32x4 acc[2][2];
  acc[0][0] = zero; acc[0][1] = zero; acc[1][0] = zero; acc[1][1] = zero;

  short8 ra[2], rb[2];
  auto issueLoads = [&](int k0) {
#pragma unroll
    for (int r = 0; r < 2; ++r) {
      int c = tid + 256*r;              // row = c>>3 (0..63), kchunk = c&7
      int row = c >> 3, kc = c & 7;
      int gk = k0 + kc*8;
      {
        int gm = m0 + row;
        const short* src = A + (long)gm * p.lda + gk;
        if (gm < p.M && gk + 8 <= kEnd) {
          ra[r] = *(const short8*)src;
        } else {
          short8 t = {0,0,0,0,0,0,0,0};
          if (gm < p.M) {
#pragma unroll
            for (int j = 0; j < 8; ++j) if (gk + j < kEnd) t[j] = src[j];
          }
          ra[r] = t;
        }
      }
      {
        int gn = n0 + row;
        const short* src = B + (long)gn * p.ldb + gk;
        if (gn < p.N && gk + 8 <= kEnd) {
          rb[r] = *(const short8*)src;
        } else {
          short8 t = {0,0,0,0,0,0,0,0};
          if (gn < p.N) {
#pragma unroll
            for (int j = 0; j < 8; ++j) if (gk + j < kEnd) t[j] = src[j];
          }
          rb[r] = t;
        }
      }
    }
  };

  issueLoads(kBeg);
  for (int k0 = kBeg; k0 < kEnd; k0 += 64) {
#pragma unroll
    for (int r = 0; r < 2; ++r) {
      int c = tid + 256*r;
      int row = c >> 3, kc = c & 7;
      *(short8*)&As[row*72 + kc*8] = ra[r];
      *(short8*)&Bs[row*72 + kc*8] = rb[r];
    }
    __syncthreads();
    if (k0 + 64 < kEnd) issueLoads(k0 + 64);   // prefetch next stage into regs
#pragma unroll
    for (int ks = 0; ks < 2; ++ks) {
      short8 a0 = *(const short8*)&As[(wm +      ln)*72 + ks*32 + quad*8];
      short8 a1 = *(const short8*)&As[(wm + 16 + ln)*72 + ks*32 + quad*8];
      short8 b0 = *(const short8*)&Bs[(wn +      ln)*72 + ks*32 + quad*8];
      short8 b1 = *(const short8*)&Bs[(wn + 16 + ln)*72 + ks*32 + quad*8];
      acc[0][0] = __builtin_amdgcn_mfma_f32_16x16x32_bf16(a0, b0, acc[0][0], 0, 0, 0);
      acc[0][1] = __builtin_amdgcn_mfma_f32_16x16x32_bf16(a0, b1, acc[0][1], 0, 0, 0);
      acc[1][0] = __builtin_amdgcn_mfma_f32_16x16x32_bf16(a1, b0, acc[1][0], 0, 0, 0);
      acc[1][1] = __builtin_amdgcn_mfma_f32_16x16x32_bf16(a1, b1, acc[1][1], 0, 0, 0);
    }
    __syncthreads();
  }

  // C/D layout: col = lane&15, row = quad*4 + reg  [verified m89/m91]
#pragma unroll
  for (int mi = 0; mi < 2; ++mi)
#pragma unroll
    for (int ni = 0; ni < 2; ++ni)
#pragma unroll
      for (int reg = 0; reg < 4; ++reg) {
        int gm = m0 + wm + mi*16 + quad*4 + reg;
        int gn = n0 + wn + ni*16 + ln;
        if (gm >= p.M || gn >= p.N) continue;
        long co = cbase + (long)gm * p.ldc + gn;
        float v = acc[mi][ni][reg] * p.alpha;
        if (!PART) v = epi_apply(EPI, p, E, co, gm, gn, v);
        if (OUTBF) ((short*)p.C)[co] = f2bf(v);
        else       p.C[co] = v;
      }
}

// --------------------------------------------- 128x128 tile (big GEMMs)
// 4 waves, each owns a 64x64 output (acc[4][4]); reuse 4 per ds_read.
template<int EPI, bool PART, bool OUTBF>
__global__ __launch_bounds__(256) void gemm_mfma128(GemmM p) {
  int bz = blockIdx.z;
  int split = 0;
  if (PART) { split = bz % p.nSplit; bz /= p.nSplit; }
  int b1 = bz % p.innerB, b0 = bz / p.innerB;
  const short* A = p.A + b0*p.sA0 + b1*p.sA1;
  const short* B = p.B + b0*p.sB0 + b1*p.sB1;
  long cbase = b0*p.sC0 + b1*p.sC1 + (PART ? (long)split * p.partStride : 0);
  const float* E = p.E;

  int kBeg = PART ? split * p.splitLen : 0;
  int kEnd = PART ? min(p.K, kBeg + p.splitLen) : p.K;

  __shared__ short As[128*72];  // rows = m (128), cols = k (64) + pad 8
  __shared__ short Bs[128*72];

  int tid  = threadIdx.x;
  int lane = tid & 63, widx = tid >> 6;
  int quad = lane >> 4, ln = lane & 15;
  int wm = (widx >> 1) * 64, wn = (widx & 1) * 64;
  int n0 = blockIdx.x * 128, m0 = blockIdx.y * 128;

  f32x4 zero = {0.f, 0.f, 0.f, 0.f};
  f32x4 acc[4][4];
#pragma unroll
  for (int i = 0; i < 4; ++i)
#pragma unroll
    for (int j = 0; j < 4; ++j) acc[i][j] = zero;

  short8 ra[4], rb[4];
  auto issueLoads = [&](int k0) {
#pragma unroll
    for (int r = 0; r < 4; ++r) {
      int c = tid + 256*r;              // row = c>>3 (0..127), kchunk = c&7
      int row = c >> 3, kc = c & 7;
      int gk = k0 + kc*8;
      {
        int gm = m0 + row;
        const short* src = A + (long)gm * p.lda + gk;
        if (gm < p.M && gk + 8 <= kEnd) {
          ra[r] = *(const short8*)src;
        } else {
          short8 t = {0,0,0,0,0,0,0,0};
          if (gm < p.M) {
#pragma unroll
            for (int j = 0; j < 8; ++j) if (gk + j < kEnd) t[j] = src[j];
          }
          ra[r] = t;
        }
      }
      {
        int gn = n0 + row;
        const short* src = B + (long)gn * p.ldb + gk;
        if (gn < p.N && gk + 8 <= kEnd) {
          rb[r] = *(const short8*)src;
        } else {
          short8 t = {0,0,0,0,0,0,0,0};
          if (gn < p.N) {
#pragma unroll
            for (int j = 0; j < 8; ++j) if (gk + j < kEnd) t[j] = src[j];
          }
          rb[r] = t;
        }
      }
    }
  };

  issueLoads(kBeg);
  for (int k0 = kBeg; k0 < kEnd; k0 += 64) {
#pragma unroll
    for (int r = 0; r < 4; ++r) {
      int c = tid + 256*r;
      int row = c >> 3, kc = c & 7;
      *(short8*)&As[row*72 + kc*8] = ra[r];
      *(short8*)&Bs[row*72 + kc*8] = rb[r];
    }
    __syncthreads();
    if (k0 + 64 < kEnd) issueLoads(k0 + 64);   // prefetch next stage into regs
#pragma unroll
    for (int ks = 0; ks < 2; ++ks) {
      short8 a[4], b[4];
#pragma unroll
      for (int i = 0; i < 4; ++i) {
        a[i] = *(const short8*)&As[(wm + i*16 + ln)*72 + ks*32 + quad*8];
        b[i] = *(const short8*)&Bs[(wn + i*16 + ln)*72 + ks*32 + quad*8];
      }
#pragma unroll
      for (int mi = 0; mi < 4; ++mi)
#pragma unroll
        for (int ni = 0; ni < 4; ++ni)
          acc[mi][ni] = __builtin_amdgcn_mfma_f32_16x16x32_bf16(a[mi], b[ni], acc[mi][ni], 0, 0, 0);
    }
    __syncthreads();
  }

#pragma unroll
  for (int mi = 0; mi < 4; ++mi)
#pragma unroll
    for (int ni = 0; ni < 4; ++ni)
#pragma unroll
      for (int reg = 0; reg < 4; ++reg) {
        int gm = m0 + wm + mi*16 + quad*4 + reg;
        int gn = n0 + wn + ni*16 + ln;
        if (gm >= p.M || gn >= p.N) continue;
        long co = cbase + (long)gm * p.ldc + gn;
        float v = acc[mi][ni][reg] * p.alpha;
        if (!PART) v = epi_apply(EPI, p, E, co, gm, gn, v);
        if (OUTBF) ((short*)p.C)[co] = f2bf(v);
        else       p.C[co] = v;
      }
}

static GemmM mkm(const short* A, const short* B, float* C,
                 int M, int N, int K, int lda, int ldb, int ldc) {
  GemmM p; p.A = A; p.B = B; p.C = C; p.E = nullptr;
  p.M = M; p.N = N; p.K = K; p.lda = lda; p.ldb = ldb; p.ldc = ldc;
  p.sA0 = p.sA1 = p.sB0 = p.sB1 = p.sC0 = p.sC1 = 0;
  p.innerB = 1; p.ldE = 0; p.rowsPB = 1; p.alpha = 1.f;
  p.nSplit = 1; p.splitLen = 0; p.partStride = 0;
  return p;
}

// 64-tile: only attention shapes (EPI 0, optional bf16 out)
static void run_gemm64(hipStream_t s, bool outbf, const GemmM& p, int nb) {
  dim3 g((p.N + 63)/64, (p.M + 63)/64, nb), b(256, 1, 1);
  if (outbf) gemm_mfma<0,false,true><<<g,b,0,s>>>(p);
  else       gemm_mfma<0,false,false><<<g,b,0,s>>>(p);
}

// 128-tile: big GEMMs
static void run_gemm128(hipStream_t s, int epi, bool outbf, const GemmM& p, int nb) {
  dim3 g((p.N + 127)/128, (p.M + 127)/128, nb), b(256, 1, 1);
  if (outbf) {
    if (epi == 3) gemm_mfma128<3,false,true><<<g,b,0,s>>>(p);
    else          gemm_mfma128<0,false,true><<<g,b,0,s>>>(p);
    return;
  }
  switch (epi) {
    case 0: gemm_mfma128<0,false,false><<<g,b,0,s>>>(p); break;
    case 1: gemm_mfma128<1,false,false><<<g,b,0,s>>>(p); break;
    case 4: gemm_mfma128<4,false,false><<<g,b,0,s>>>(p); break;
    case 5: gemm_mfma128<5,false,false><<<g,b,0,s>>>(p); break;
  }
}

static void run_gemm128_part(hipStream_t s, const GemmM& p, int nb) {
  dim3 g((p.N + 127)/128, (p.M + 127)/128, nb * p.nSplit), b(256, 1, 1);
  gemm_mfma128<0,true,false><<<g,b,0,s>>>(p);
}

// ------------------------------------------------------------- split-K reduce
template<int EPI>
__global__ __launch_bounds__(256) void reduce_split(
    const float* __restrict__ part, long partStride, int S,
    float* __restrict__ C, const float* __restrict__ E,
    int Mv, int Nv, int ldc, long sC0, long sC1, int innerB,
    int ldE, int rowsPB, int total) {
  int idx = blockIdx.x*256 + threadIdx.x;
  if (idx >= total) return;
  int n = idx % Nv;
  int m = (idx / Nv) % Mv;
  int bz = idx / (Nv * Mv);
  int b1 = bz % innerB, b0 = bz / innerB;
  long co = b0*sC0 + b1*sC1 + (long)m*ldc + n;
  float v = 0.f;
  for (int s = 0; s < S; ++s) v += part[(long)s*partStride + co];
  if (EPI == 1) v += E[n];
  else if (EPI == 3) v = 0.5f*v*(1.f + erff(v*0.70710678118654752f));
  else if (EPI == 4) v += E[(long)m*ldE + n];
  else if (EPI == 5) v = C[co] + E[(long)(m / rowsPB)*ldE + n] * v;
  C[co] = v;
}

static void run_reduce(hipStream_t st, int epi, const float* part, long pStride, int S,
                       float* C, const float* E, int Mv, int Nv, int ldc,
                       long sC0, long sC1, int innerB, int nbTot, int ldE, int rowsPB) {
  int total = nbTot * Mv * Nv;
  dim3 g((total + 255)/256), b(256);
  switch (epi) {
    case 0: reduce_split<0><<<g,b,0,st>>>(part,pStride,S,C,E,Mv,Nv,ldc,sC0,sC1,innerB,ldE,rowsPB,total); break;
    case 1: reduce_split<1><<<g,b,0,st>>>(part,pStride,S,C,E,Mv,Nv,ldc,sC0,sC1,innerB,ldE,rowsPB,total); break;
    case 4: reduce_split<4><<<g,b,0,st>>>(part,pStride,S,C,E,Mv,Nv,ldc,sC0,sC1,innerB,ldE,rowsPB,total); break;
    case 5: reduce_split<5><<<g,b,0,st>>>(part,pStride,S,C,E,Mv,Nv,ldc,sC0,sC1,innerB,ldE,rowsPB,total); break;
  }
}

// ------------------------------------------------------ fp32 -> bf16 convert
__global__ __launch_bounds__(256) void cvt_bf16(const float* __restrict__ src,
                                                short* __restrict__ dst, int n8) {
  int i = blockIdx.x*256 + threadIdx.x;
  if (i >= n8) return;
  float4 a = ((const float4*)src)[2*i];
  float4 b = ((const float4*)src)[2*i + 1];
  short8 o;
  o[0]=f2bf(a.x); o[1]=f2bf(a.y); o[2]=f2bf(a.z); o[3]=f2bf(a.w);
  o[4]=f2bf(b.x); o[5]=f2bf(b.y); o[6]=f2bf(b.z); o[7]=f2bf(b.w);
  *(short8*)(dst + 8L*i) = o;
}

static void cvt(hipStream_t s, const float* src, short* dst, long n) {
  long n8 = n / 8;
  cvt_bf16<<<dim3((unsigned)((n8 + 255)/256)), dim3(256), 0, s>>>(src, dst, (int)n8);
}

// ================================================================ skinny GEMV4
template<int EPI>
__global__ __launch_bounds__(256) void gemv4(const float* __restrict__ A,
                                             const float* __restrict__ B,
                                             float* __restrict__ C,
                                             const float* __restrict__ bias,
                                             int N, int K, int ldc) {
  int wave = threadIdx.x >> 6, lane = threadIdx.x & 63;
  int n = blockIdx.x * 4 + wave;
  if (n >= N) return;
  const float* Brow = B + (long)n * K;
  float acc0 = 0.f, acc1 = 0.f, acc2 = 0.f, acc3 = 0.f;
  for (int k = lane * 4; k < K; k += 256) {
    float4 b = *(const float4*)(Brow + k);
    float4 a0 = *(const float4*)(A + 0*K + k);
    float4 a1 = *(const float4*)(A + 1*K + k);
    float4 a2 = *(const float4*)(A + 2*K + k);
    float4 a3 = *(const float4*)(A + 3*K + k);
    acc0 += a0.x*b.x + a0.y*b.y + a0.z*b.z + a0.w*b.w;
    acc1 += a1.x*b.x + a1.y*b.y + a1.z*b.z + a1.w*b.w;
    acc2 += a2.x*b.x + a2.y*b.y + a2.z*b.z + a2.w*b.w;
    acc3 += a3.x*b.x + a3.y*b.y + a3.z*b.z + a3.w*b.w;
  }
#pragma unroll
  for (int off = 32; off; off >>= 1) {
    acc0 += __shfl_xor(acc0, off);
    acc1 += __shfl_xor(acc1, off);
    acc2 += __shfl_xor(acc2, off);
    acc3 += __shfl_xor(acc3, off);
  }
  if (lane == 0) {
    float bs = bias[n];
    float v[4] = {acc0 + bs, acc1 + bs, acc2 + bs, acc3 + bs};
#pragma unroll
    for (int m = 0; m < 4; ++m) {
      float x = v[m];
      if (EPI == 2) x = x / (1.f + expf(-x));
      C[(long)m * ldc + n] = x;
    }
  }
}

// ---------------------------------------------------------------- small kernels
__global__ void embed_text_cls(const float* __restrict__ Wtok, const int* __restrict__ toks,
                               const float* __restrict__ pos_text, const float* __restrict__ cls_tok,
                               float* __restrict__ x) {
  int idx = blockIdx.x*256 + threadIdx.x;           // over B*65*DIM
  int d = idx % kDim;
  int t = (idx / kDim) % (kText + 1);
  int b = idx / (kDim * (kText + 1));
  float v;
  if (t < kText) {
    int tok = toks[b*kText + t];
    v = Wtok[(long)d*kVocab + tok] + pos_text[(long)t*kDim + d];
  } else {
    v = cls_tok[d];
  }
  x[((long)b*kTok + t)*kDim + d] = v;
}

__global__ void extract_patches(const float* __restrict__ img, short* __restrict__ pat) {
  int idx = blockIdx.x*256 + threadIdx.x;           // B*256*768
  int k = idx % 768;
  int p = (idx/768) % kNp;
  int b = idx/(768*kNp);
  int c = k >> 8, py = (k >> 4) & 15, px = k & 15;
  int hp = p >> 4, wp = p & 15;
  pat[idx] = f2bf(img[(((long)(b*3 + c))*kImg + hp*16 + py)*kImg + wp*16 + px]);
}

__global__ void time_freqs(const int* __restrict__ ts, float* __restrict__ temb) {
  int b = blockIdx.x, i = threadIdx.x;              // 128 threads
  float f = expf(-9.210340371976184f * (float)i / 128.f);
  float a = (float)ts[b] * f;
  temb[b*kTdim + i] = cosf(a);
  temb[b*kTdim + 128 + i] = sinf(a);
}

__global__ void silu_kernel(const float* __restrict__ in, float* __restrict__ outp, int n) {
  int i = blockIdx.x*256 + threadIdx.x;
  if (i < n) { float x = in[i]; outp[i] = x / (1.f + expf(-x)); }
}

__device__ __forceinline__ float block_sum(float v) {
  __shared__ float sh[4];
  for (int off = 32; off; off >>= 1) v += __shfl_down(v, off);
  if ((threadIdx.x & 63) == 0) sh[threadIdx.x >> 6] = v;
  __syncthreads();
  float s = sh[0] + sh[1] + sh[2] + sh[3];
  __syncthreads();
  return s;
}

__global__ __launch_bounds__(256) void ln_mod_kernel(
    const float* __restrict__ x, const float* __restrict__ g, const float* __restrict__ be,
    const float* __restrict__ mod, int shOff, int scOff, short* __restrict__ outp) {
  int row = blockIdx.x;                 // b*321 + t
  int b = row / kTok;
  const float* xr = x + (long)row*kDim;
  float s = 0.f, s2 = 0.f;
  for (int i = threadIdx.x; i < kDim; i += 256) { float v = xr[i]; s += v; s2 += v*v; }
  s = block_sum(s); s2 = block_sum(s2);
  float m = s / kDim;
  float inv = rsqrtf(s2 / kDim - m*m + kEps);
  const float* mb = mod + (long)b*(6*kDim);
  for (int i = threadIdx.x; i < kDim; i += 256) {
    float xn = (xr[i] - m)*inv*g[i] + be[i];
    outp[(long)row*kDim + i] = f2bf(xn*(1.f + mb[scOff + i]) + mb[shOff + i]);
  }
}

__global__ __launch_bounds__(256) void final_ln_kernel(
    const float* __restrict__ x, const float* __restrict__ g, const float* __restrict__ be,
    short* __restrict__ yn) {
  int row = blockIdx.x;                 // b*256 + p
  int b = row / kNp, p = row % kNp;
  const float* xr = x + ((long)(b*kTok + kText + 1 + p))*kDim;
  float s = 0.f, s2 = 0.f;
  for (int i = threadIdx.x; i < kDim; i += 256) { float v = xr[i]; s += v; s2 += v*v; }
  s = block_sum(s); s2 = block_sum(s2);
  float m = s / kDim;
  float inv = rsqrtf(s2 / kDim - m*m + kEps);
  for (int i = threadIdx.x; i < kDim; i += 256)
    yn[(long)row*kDim + i] = f2bf((xr[i] - m)*inv*g[i] + be[i]);
}

// RoPE: read fused fp32 QKV [row][3072], write bf16 q,k [row][1024] (no in-place race)
__global__ __launch_bounds__(256) void rope_bf16(const float* __restrict__ qkv,
                                                 short* __restrict__ qb,
                                                 short* __restrict__ kb) {
  int idx = blockIdx.x*256 + threadIdx.x;          // B*321*1024
  int d = idx & (kDim - 1);
  int r = idx >> 10;                               // global row
  int n = r % kTok;
  int hd = d & 63;
  int j = hd & 31;
  float inv = expf(-9.210340371976184f * (float)j / 32.f);
  float ang = (float)n * inv;
  float c = cosf(ang), s = sinf(ang);
  const float* row = qkv + (long)r * (3*kDim);
  int base = d - hd;
  float qv = row[d], kv = row[kDim + d];
  float qr, kr;
  if (hd < 32) { qr = -row[base + 2*hd + 1];      kr = -row[kDim + base + 2*hd + 1]; }
  else         { qr =  row[base + 2*(hd - 32)];   kr =  row[kDim + base + 2*(hd - 32)]; }
  qb[idx] = f2bf(qv*c + qr*s);
  kb[idx] = f2bf(kv*c + kr*s);
}

// V slice of fused QKV -> vtb[b][h][hd][tok(pad 328)] bf16
__global__ __launch_bounds__(256) void vtrans_kernel(const float* __restrict__ qkv,
                                                     short* __restrict__ vtb) {
  int idx = blockIdx.x*256 + threadIdx.x;          // B*16*64*328
  int tok = idx % kScLd;
  int hd  = (idx / kScLd) % kHd;
  int h   = (idx / (kScLd*kHd)) % kHeads;
  int b   = idx / (kScLd*kHd*kHeads);
  float v = 0.f;
  if (tok < kTok) v = qkv[((long)(b*kTok + tok))*(3*kDim) + 2*kDim + h*kHd + hd];
  vtb[idx] = f2bf(v);
}

__global__ void softmax_rows(float* __restrict__ sc, short* __restrict__ dst,
                             int rowLen, int rowStride) {
  long row = blockIdx.x;
  float* r = sc + row*rowStride;
  short* d = dst + row*rowStride;
  int t = threadIdx.x;                              // 64 threads = 1 wave
  float mx = -1e30f;
  for (int i = t; i < rowLen; i += 64) mx = fmaxf(mx, r[i]);
  for (int off = 32; off; off >>= 1) mx = fmaxf(mx, __shfl_xor(mx, off));
  float sum = 0.f;
  for (int i = t; i < rowLen; i += 64) { float e = expf(r[i] - mx); r[i] = e; sum += e; }
  for (int off = 32; off; off >>= 1) sum += __shfl_xor(sum, off);
  float invs = 1.f / sum;
  for (int i = t; i < rowLen; i += 64) d[i] = f2bf(r[i] * invs);
}

__global__ void unpatchify(const float* __restrict__ op, float* __restrict__ outp) {
  int idx = blockIdx.x*256 + threadIdx.x;           // B*3*256*256
  int w = idx & 255;
  int h = (idx >> 8) & 255;
  int c = (idx >> 16) % 3;
  int b = idx / (3 * kImg * kImg);
  int hp = h >> 4, py = h & 15, wp = w >> 4, px = w & 15;
  outp[idx] = op[((long)(b*kNp + hp*16 + wp))*768 + c*256 + py*16 + px];
}

// ---------------------------------------------------------------- launch
extern "C" void kernel_launch(void* const* d_in, const int* in_sizes, int n_in,
                              void* d_out, int out_size, void* d_ws, size_t ws_size,
                              hipStream_t stream) {
  (void)in_sizes; (void)n_in; (void)out_size;
  const float* noisy    = (const float*)d_in[0];
  const int*   toks     = (const int*)d_in[1];
  const int*   tsteps   = (const int*)d_in[2];
  const float* W_tok    = (const float*)d_in[3];
  const float* pos_text = (const float*)d_in[4];
  const float* W_patch  = (const float*)d_in[5];
  const float* pos_img  = (const float*)d_in[6];
  const float* cls_tok  = (const float*)d_in[7];
  const float* W_t1     = (const float*)d_in[8];
  const float* b_t1     = (const float*)d_in[9];
  const float* W_t2     = (const float*)d_in[10];
  const float* b_t2     = (const float*)d_in[11];
  const float* ln1_g    = (const float*)d_in[12];
  const float* ln1_b    = (const float*)d_in[13];
  const float* Wq       = (const float*)d_in[14];
  const float* Wk       = (const float*)d_in[15];
  const float* Wv       = (const float*)d_in[16];
  const float* Wo       = (const float*)d_in[17];
  const float* ln2_g    = (const float*)d_in[18];
  const float* ln2_b    = (const float*)d_in[19];
  const float* Wm1      = (const float*)d_in[20];
  const float* Wm2      = (const float*)d_in[21];
  const float* Wada     = (const float*)d_in[22];
  const float* b_ada    = (const float*)d_in[23];
  const float* fn_g     = (const float*)d_in[24];
  const float* fn_b     = (const float*)d_in[25];
  const float* W_final  = (const float*)d_in[26];
  const float* b_final  = (const float*)d_in[27];
  float* out = (float*)d_out;

  float* ws = (float*)d_ws;
  auto alloc = [&](long nf) { float* r = ws; ws += nf; return r; };

  const long seqSz = (long)kBn * kTok * kDim;            // 1,314,816
  float* x    = alloc(seqSz);                            // fp32 residual
  float* qkv  = alloc((long)kBn*kTok*3*kDim);            // fused QKV fp32
  float* sc   = alloc((long)kBn*kHeads*kTok*kScLd);      // fp32 scores
  short* xnb  = (short*)alloc(seqSz/2);                  // bf16 ln-mod out
  short* qb   = (short*)alloc(seqSz/2);
  short* kb   = (short*)alloc(seqSz/2);
  short* ob   = (short*)alloc(seqSz/2);                  // bf16 attn out
  short* vtb  = (short*)alloc((long)kBn*kHeads*kHd*kScLd/2);
  short* scb  = (short*)alloc((long)kBn*kHeads*kTok*kScLd/2);
  short* patb = (short*)alloc((long)kBn*kNp*768/2);
  short* ynb  = (short*)alloc((long)kBn*kNp*kDim/2);
  short* wbuf = (short*)alloc((long)kMlp*kDim/2);        // bf16 weight staging (4M shorts)
  float* temb = alloc(kBn*kTdim);
  float* t1   = alloc(kBn*kDim);
  float* temb2= alloc(kBn*kDim);
  float* st   = alloc(kBn*kDim);
  float* mod  = alloc(2L*kBn*6*kDim);
  short* hb   = (short*)sc;       // MLP hidden aliases scores (dead by MLP1)
  float* outp = qkv;              // final-proj out aliases qkv (dead by final)

  const long scrStride = seqSz;                          // max split-K partial extent
  float* scr = alloc(4*scrStride);
  bool split_ok = ((char*)ws - (char*)d_ws) <= (long)ws_size;

  // --- embeddings
  embed_text_cls<<<(kBn*(kText+1)*kDim)/256, 256, 0, stream>>>(W_tok, toks, pos_text, cls_tok, x);
  extract_patches<<<(kBn*kNp*768)/256, 256, 0, stream>>>(noisy, patb);
  cvt(stream, W_patch, wbuf, (long)kDim*768);
  {
    GemmM p = mkm(patb, wbuf, split_ok ? scr : (x + (kText+1)*kDim),
                  kNp, kDim, 768, 768, 768, kDim);
    p.sA0 = (long)kNp*768; p.sC0 = (long)kTok*kDim;
    if (split_ok) {
      p.nSplit = 3; p.splitLen = 256; p.partStride = scrStride;
      run_gemm128_part(stream, p, kBn);
      run_reduce(stream, 4, scr, scrStride, 3, x + (kText+1)*kDim, pos_img,
                 kNp, kDim, kDim, (long)kTok*kDim, 0, 1, kBn, kDim, 1);
    } else {
      p.E = pos_img; p.ldE = kDim;
      run_gemm128(stream, 4, false, p, kBn);
    }
  }
  // --- time embedding (skinny GEMV path)
  time_freqs<<<kBn, 128, 0, stream>>>(tsteps, temb);
  gemv4<2><<<kDim/4, 256, 0, stream>>>(temb, W_t1, t1, b_t1, kDim, kTdim, kDim);
  gemv4<1><<<kDim/4, 256, 0, stream>>>(t1, W_t2, temb2, b_t2, kDim, kDim, kDim);
  silu_kernel<<<(kBn*kDim + 255)/256, 256, 0, stream>>>(temb2, st, kBn*kDim);

  for (int l = 0; l < 2; ++l) {
    const float* Wq_l  = Wq  + (long)l*kDim*kDim;
    const float* Wk_l  = Wk  + (long)l*kDim*kDim;
    const float* Wv_l  = Wv  + (long)l*kDim*kDim;
    const float* Wo_l  = Wo  + (long)l*kDim*kDim;
    const float* Wm1_l = Wm1 + (long)l*kMlp*kDim;
    const float* Wm2_l = Wm2 + (long)l*kDim*kMlp;
    float* mod_l = mod + (long)l*kBn*6*kDim;

    gemv4<1><<<(6*kDim)/4, 256, 0, stream>>>(st, Wada + (long)l*6*kDim*kDim, mod_l,
                                             b_ada + (long)l*6*kDim, 6*kDim, kDim, 6*kDim);

    ln_mod_kernel<<<kBn*kTok, 256, 0, stream>>>(x, ln1_g + l*kDim, ln1_b + l*kDim,
                                                mod_l, 0, kDim, xnb);
    // fused QKV projection: N=3072, grid 24x11 -> no split-K, no reduce
    cvt(stream, Wq_l, wbuf,                     (long)kDim*kDim);
    cvt(stream, Wk_l, wbuf +   (long)kDim*kDim, (long)kDim*kDim);
    cvt(stream, Wv_l, wbuf + 2L*(long)kDim*kDim, (long)kDim*kDim);
    {
      GemmM p = mkm(xnb, wbuf, qkv, kBn*kTok, 3*kDim, kDim, kDim, kDim, 3*kDim);
      run_gemm128(stream, 0, false, p, 1);
    }
    rope_bf16<<<(int)(seqSz/256), 256, 0, stream>>>(qkv, qb, kb);
    vtrans_kernel<<<(kBn*kHeads*kHd*kScLd)/256, 256, 0, stream>>>(qkv, vtb);

    { // scores = 0.125 * q @ k^T per (b,h), rows padded to 328
      GemmM p = mkm(qb, kb, sc, kTok, kTok, kHd, kDim, kDim, kScLd);
      p.sA0 = (long)kTok*kDim; p.sA1 = kHd;
      p.sB0 = (long)kTok*kDim; p.sB1 = kHd;
      p.sC0 = (long)kHeads*kTok*kScLd; p.sC1 = (long)kTok*kScLd;
      p.innerB = kHeads; p.alpha = 0.125f;
      run_gemm64(stream, false, p, kBn*kHeads);
    }
    softmax_rows<<<kBn*kHeads*kTok, 64, 0, stream>>>(sc, scb, kTok, kScLd);
    { // o = P @ V per (b,h), bf16 out
      GemmM p = mkm(scb, vtb, (float*)ob, kTok, kHd, kTok, kScLd, kScLd, kDim);
      p.sA0 = (long)kHeads*kTok*kScLd; p.sA1 = (long)kTok*kScLd;
      p.sB0 = (long)kHeads*kHd*kScLd;  p.sB1 = (long)kHd*kScLd;
      p.sC0 = (long)kTok*kDim;         p.sC1 = kHd;
      p.innerB = kHeads;
      run_gemm64(stream, true, p, kBn*kHeads);
    }
    cvt(stream, Wo_l, wbuf, (long)kDim*kDim);
    { // x += g_msa * (o @ Wo^T)   (split-K x4)
      GemmM p = mkm(ob, wbuf, split_ok ? scr : x, kBn*kTok, kDim, kDim, kDim, kDim, kDim);
      if (split_ok) {
        p.nSplit = 4; p.splitLen = 256; p.partStride = scrStride;
        run_gemm128_part(stream, p, 1);
        run_reduce(stream, 5, scr, scrStride, 4, x, mod_l + 2*kDim,
                   kBn*kTok, kDim, kDim, 0, 0, 1, 1, 6*kDim, kTok);
      } else {
        p.E = mod_l + 2*kDim; p.ldE = 6*kDim; p.rowsPB = kTok;
        run_gemm128(stream, 5, false, p, 1);
      }
    }
    ln_mod_kernel<<<kBn*kTok, 256, 0, stream>>>(x, ln2_g + l*kDim, ln2_b + l*kDim,
                                                mod_l, 3*kDim, 4*kDim, xnb);
    cvt(stream, Wm1_l, wbuf, (long)kMlp*kDim);
    { // MLP1 + gelu, bf16 hidden
      GemmM p = mkm(xnb, wbuf, (float*)hb, kBn*kTok, kMlp, kDim, kDim, kDim, kMlp);
      run_gemm128(stream, 3, true, p, 1);
    }
    cvt(stream, Wm2_l, wbuf, (long)kMlp*kDim);
    { // MLP2 (split-K x4, K=4096)
      GemmM p = mkm(hb, wbuf, split_ok ? scr : x, kBn*kTok, kDim, kMlp, kMlp, kMlp, kDim);
      if (split_ok) {
        p.nSplit = 4; p.splitLen = 1024; p.partStride = scrStride;
        run_gemm128_part(stream, p, 1);
        run_reduce(stream, 5, scr, scrStride, 4, x, mod_l + 5*kDim,
                   kBn*kTok, kDim, kDim, 0, 0, 1, 1, 6*kDim, kTok);
      } else {
        p.E = mod_l + 5*kDim; p.ldE = 6*kDim; p.rowsPB = kTok;
        run_gemm128(stream, 5, false, p, 1);
      }
    }
  }

  final_ln_kernel<<<kBn*kNp, 256, 0, stream>>>(x, fn_g, fn_b, ynb);
  cvt(stream, W_final, wbuf, (long)768*kDim);
  { // final projection (split-K x4)
    GemmM p = mkm(ynb, wbuf, split_ok ? scr : outp, kBn*kNp, 768, kDim, kDim, kDim, 768);
    if (split_ok) {
      p.nSplit = 4; p.splitLen = 256; p.partStride = (long)kBn*kNp*768;
      run_gemm128_part(stream, p, 1);
      run_reduce(stream, 1, scr, (long)kBn*kNp*768, 4, outp, b_final,
                 kBn*kNp, 768, 768, 0, 0, 1, 1, 0, 1);
    } else {
      p.E = b_final;
      run_gemm128(stream, 1, false, p, 1);
    }
  }
  unpatchify<<<(kBn*3*kImg*kImg)/256, 256, 0, stream>>>(outp, out);
}

// Round 3
// 790.515 us; speedup vs baseline: 1.1048x; 1.1048x over previous
//
#include <hip/hip_runtime.h>
#include <math.h>

constexpr int kBn    = 4;
constexpr int kText  = 64;
constexpr int kImg   = 256;
constexpr int kDim   = 1024;
constexpr int kHeads = 16;
constexpr int kHd    = 64;
constexpr int kNp    = 256;    // patches
constexpr int kTok   = 321;    // 64 text + 1 cls + 256 img
constexpr int kVocab = 50000;
constexpr int kTdim  = 256;
constexpr int kMlp   = 4096;
constexpr int kScLd  = 328;    // score row stride (321 padded to mult of 8)
constexpr float kEps = 1e-5f;

typedef __attribute__((ext_vector_type(8))) short short8;
typedef __attribute__((ext_vector_type(4))) float f32x4;

// RNE float -> bf16 bits
__device__ __forceinline__ short f2bf(float x) {
  unsigned u = __builtin_bit_cast(unsigned, x);
  unsigned r = (u + 0x7FFFu + ((u >> 16) & 1u)) >> 16;
  return (short)r;
}

// async global->LDS, 16B per lane, dest = base + lane*16 (wave-uniform base)
__device__ __forceinline__ void glds16(const short* g, short* l) {
  __builtin_amdgcn_global_load_lds(
      (const __attribute__((address_space(1))) unsigned int*)g,
      (__attribute__((address_space(3))) unsigned int*)l, 16, 0, 0);
}

// =================================================================== MFMA GEMM
// C[m][n] = alpha * sum_k A[m][k] * B[n][k]   (A,B bf16 in memory, fp32 accum)
// EPI: 0 none | 1 +bias[n] | 3 gelu | 4 +E[m][n] | 5 gated residual
struct GemmM {
  const short* A; const short* B; float* C; const float* E;
  int M, N, K, lda, ldb, ldc;
  long sA0, sA1, sB0, sB1, sC0, sC1;
  int innerB, ldE, rowsPB;
  float alpha;
  int nSplit, splitLen;
  long partStride;
};

__device__ __forceinline__ float epi_apply(int EPI, const GemmM& p, const float* E,
                                           long co, int gm, int gn, float v) {
  if (EPI == 1) v += E[gn];
  else if (EPI == 3) v = 0.5f*v*(1.f + erff(v*0.70710678118654752f));
  else if (EPI == 4) v += E[(long)gm*p.ldE + gn];
  else if (EPI == 5) v = p.C[co] + E[(long)(gm / p.rowsPB)*p.ldE + gn] * v;
  return v;
}

// ------------------- 64x64 tile, global_load_lds staging (requires K%64==0) --
// LDS layout: linear [64 rows][128B], content XOR-swizzled:
//   LDS[row*128 + (cb ^ ((row&7)<<4))] = A[row][cb/2]
// Write side: global source pre-swizzled per lane; read side applies same XOR.
// M/N edge rows read garbage (in-workspace) -> garbage C rows/cols, skipped on store.
template<int EPI, bool PART, bool OUTBF>
__global__ __launch_bounds__(256) void gemm_gl(GemmM p) {
  int bz = blockIdx.z;
  int split = 0;
  if (PART) { split = bz % p.nSplit; bz /= p.nSplit; }
  int b1 = bz % p.innerB, b0 = bz / p.innerB;
  const short* A = p.A + b0*p.sA0 + b1*p.sA1;
  const short* B = p.B + b0*p.sB0 + b1*p.sB1;
  long cbase = b0*p.sC0 + b1*p.sC1 + (PART ? (long)split * p.partStride : 0);
  const float* E = p.E;

  int kBeg = PART ? split * p.splitLen : 0;
  int kEnd = PART ? min(p.K, kBeg + p.splitLen) : p.K;

  __shared__ short As[2][64*64];
  __shared__ short Bs[2][64*64];

  int tid  = threadIdx.x;
  int lane = tid & 63, widx = tid >> 6;
  int quad = lane >> 4, ln = lane & 15;
  int wm = (widx >> 1) * 32, wn = (widx & 1) * 32;
  int n0 = blockIdx.x * 64, m0 = blockIdx.y * 64;

  // staging: wave w fills chunks {2w,2w+1} (8 rows each) of As and Bs.
  int l3 = lane >> 3, l7 = lane & 7;
  int kofs = (l7 ^ l3) * 8;                       // pre-swizzled element offset
  const short* gA0 = A + (long)(m0 + 16*widx + l3) * p.lda + kofs;
  const short* gA1 = gA0 + (long)8 * p.lda;
  const short* gB0 = B + (long)(n0 + 16*widx + l3) * p.ldb + kofs;
  const short* gB1 = gB0 + (long)8 * p.ldb;
  short* lA0 = &As[0][(2*widx)*512];
  short* lA1 = &As[0][(2*widx+1)*512];
  short* lB0 = &Bs[0][(2*widx)*512];
  short* lB1 = &Bs[0][(2*widx+1)*512];

  auto stage = [&](int buf, int k0) {
    int bo = buf * 4096;
    glds16(gA0 + k0, lA0 + bo);
    glds16(gA1 + k0, lA1 + bo);
    glds16(gB0 + k0, lB0 + bo);
    glds16(gB1 + k0, lB1 + bo);
  };

  f32x4 zero = {0.f, 0.f, 0.f, 0.f};
  f32x4 acc[2][2];
  acc[0][0] = zero; acc[0][1] = zero; acc[1][0] = zero; acc[1][1] = zero;

  stage(0, kBeg);
  int buf = 0;
  for (int k0 = kBeg; k0 < kEnd; k0 += 64) {
    if (k0 + 64 < kEnd) stage(buf ^ 1, k0 + 64);
    __syncthreads();                 // drains vmcnt -> buf ready
    const char* Ab = (const char*)&As[buf][0];
    const char* Bb = (const char*)&Bs[buf][0];
#pragma unroll
    for (int ks = 0; ks < 2; ++ks) {
      int cb = ks*64 + quad*16;
      int r0 = wm + ln, r1 = wm + 16 + ln, r2 = wn + ln, r3 = wn + 16 + ln;
      short8 a0 = *(const short8*)(Ab + r0*128 + (cb ^ ((r0 & 7) << 4)));
      short8 a1 = *(const short8*)(Ab + r1*128 + (cb ^ ((r1 & 7) << 4)));
      short8 b0 = *(const short8*)(Bb + r2*128 + (cb ^ ((r2 & 7) << 4)));
      short8 b1 = *(const short8*)(Bb + r3*128 + (cb ^ ((r3 & 7) << 4)));
      acc[0][0] = __builtin_amdgcn_mfma_f32_16x16x32_bf16(a0, b0, acc[0][0], 0, 0, 0);
      acc[0][1] = __builtin_amdgcn_mfma_f32_16x16x32_bf16(a0, b1, acc[0][1], 0, 0, 0);
      acc[1][0] = __builtin_amdgcn_mfma_f32_16x16x32_bf16(a1, b0, acc[1][0], 0, 0, 0);
      acc[1][1] = __builtin_amdgcn_mfma_f32_16x16x32_bf16(a1, b1, acc[1][1], 0, 0, 0);
    }
    __syncthreads();
    buf ^= 1;
  }

  // C/D layout: col = lane&15, row = quad*4 + reg  [verified m89/m91]
#pragma unroll
  for (int mi = 0; mi < 2; ++mi)
#pragma unroll
    for (int ni = 0; ni < 2; ++ni)
#pragma unroll
      for (int reg = 0; reg < 4; ++reg) {
        int gm = m0 + wm + mi*16 + quad*4 + reg;
        int gn = n0 + wn + ni*16 + ln;
        if (gm >= p.M || gn >= p.N) continue;
        long co = cbase + (long)gm * p.ldc + gn;
        float v = acc[mi][ni][reg] * p.alpha;
        if (!PART) v = epi_apply(EPI, p, E, co, gm, gn, v);
        if (OUTBF) ((short*)p.C)[co] = f2bf(v);
        else       p.C[co] = v;
      }
}

// ------------------- 64x64 reg-staged kernel with K-edge guards (PV: K=321) --
template<int EPI, bool OUTBF>
__global__ __launch_bounds__(256) void gemm_mfma(GemmM p) {
  int bz = blockIdx.z;
  int b1 = bz % p.innerB, b0 = bz / p.innerB;
  const short* A = p.A + b0*p.sA0 + b1*p.sA1;
  const short* B = p.B + b0*p.sB0 + b1*p.sB1;
  long cbase = b0*p.sC0 + b1*p.sC1;
  const float* E = p.E;
  int kEnd = p.K;

  __shared__ short As[64*72];
  __shared__ short Bs[64*72];

  int tid  = threadIdx.x;
  int lane = tid & 63, widx = tid >> 6;
  int quad = lane >> 4, ln = lane & 15;
  int wm = (widx >> 1) * 32, wn = (widx & 1) * 32;
  int n0 = blockIdx.x * 64, m0 = blockIdx.y * 64;

  f32x4 zero = {0.f, 0.f, 0.f, 0.f};
  f32x4 acc[2][2];
  acc[0][0] = zero; acc[0][1] = zero; acc[1][0] = zero; acc[1][1] = zero;

  short8 ra[2], rb[2];
  auto issueLoads = [&](int k0) {
#pragma unroll
    for (int r = 0; r < 2; ++r) {
      int c = tid + 256*r;
      int row = c >> 3, kc = c & 7;
      int gk = k0 + kc*8;
      {
        int gm = m0 + row;
        const short* src = A + (long)gm * p.lda + gk;
        if (gm < p.M && gk + 8 <= kEnd) ra[r] = *(const short8*)src;
        else {
          short8 t = {0,0,0,0,0,0,0,0};
          if (gm < p.M) {
#pragma unroll
            for (int j = 0; j < 8; ++j) if (gk + j < kEnd) t[j] = src[j];
          }
          ra[r] = t;
        }
      }
      {
        int gn = n0 + row;
        const short* src = B + (long)gn * p.ldb + gk;
        if (gn < p.N && gk + 8 <= kEnd) rb[r] = *(const short8*)src;
        else {
          short8 t = {0,0,0,0,0,0,0,0};
          if (gn < p.N) {
#pragma unroll
            for (int j = 0; j < 8; ++j) if (gk + j < kEnd) t[j] = src[j];
          }
          rb[r] = t;
        }
      }
    }
  };

  issueLoads(0);
  for (int k0 = 0; k0 < kEnd; k0 += 64) {
#pragma unroll
    for (int r = 0; r < 2; ++r) {
      int c = tid + 256*r;
      int row = c >> 3, kc = c & 7;
      *(short8*)&As[row*72 + kc*8] = ra[r];
      *(short8*)&Bs[row*72 + kc*8] = rb[r];
    }
    __syncthreads();
    if (k0 + 64 < kEnd) issueLoads(k0 + 64);
#pragma unroll
    for (int ks = 0; ks < 2; ++ks) {
      short8 a0 = *(const short8*)&As[(wm +      ln)*72 + ks*32 + quad*8];
      short8 a1 = *(const short8*)&As[(wm + 16 + ln)*72 + ks*32 + quad*8];
      short8 b0 = *(const short8*)&Bs[(wn +      ln)*72 + ks*32 + quad*8];
      short8 b1 = *(const short8*)&Bs[(wn + 16 + ln)*72 + ks*32 + quad*8];
      acc[0][0] = __builtin_amdgcn_mfma_f32_16x16x32_bf16(a0, b0, acc[0][0], 0, 0, 0);
      acc[0][1] = __builtin_amdgcn_mfma_f32_16x16x32_bf16(a0, b1, acc[0][1], 0, 0, 0);
      acc[1][0] = __builtin_amdgcn_mfma_f32_16x16x32_bf16(a1, b0, acc[1][0], 0, 0, 0);
      acc[1][1] = __builtin_amdgcn_mfma_f32_16x16x32_bf16(a1, b1, acc[1][1], 0, 0, 0);
    }
    __syncthreads();
  }

#pragma unroll
  for (int mi = 0; mi < 2; ++mi)
#pragma unroll
    for (int ni = 0; ni < 2; ++ni)
#pragma unroll
      for (int reg = 0; reg < 4; ++reg) {
        int gm = m0 + wm + mi*16 + quad*4 + reg;
        int gn = n0 + wn + ni*16 + ln;
        if (gm >= p.M || gn >= p.N) continue;
        long co = cbase + (long)gm * p.ldc + gn;
        float v = acc[mi][ni][reg] * p.alpha;
        v = epi_apply(EPI, p, E, co, gm, gn, v);
        if (OUTBF) ((short*)p.C)[co] = f2bf(v);
        else       p.C[co] = v;
      }
}

static GemmM mkm(const short* A, const short* B, float* C,
                 int M, int N, int K, int lda, int ldb, int ldc) {
  GemmM p; p.A = A; p.B = B; p.C = C; p.E = nullptr;
  p.M = M; p.N = N; p.K = K; p.lda = lda; p.ldb = ldb; p.ldc = ldc;
  p.sA0 = p.sA1 = p.sB0 = p.sB1 = p.sC0 = p.sC1 = 0;
  p.innerB = 1; p.ldE = 0; p.rowsPB = 1; p.alpha = 1.f;
  p.nSplit = 1; p.splitLen = 0; p.partStride = 0;
  return p;
}

static void run_gl(hipStream_t s, int epi, bool outbf, const GemmM& p, int nb) {
  dim3 g((p.N + 63)/64, (p.M + 63)/64, nb), b(256, 1, 1);
  if (outbf) {
    if (epi == 3) gemm_gl<3,false,true><<<g,b,0,s>>>(p);
    else          gemm_gl<0,false,true><<<g,b,0,s>>>(p);
    return;
  }
  switch (epi) {
    case 0: gemm_gl<0,false,false><<<g,b,0,s>>>(p); break;
    case 1: gemm_gl<1,false,false><<<g,b,0,s>>>(p); break;
    case 4: gemm_gl<4,false,false><<<g,b,0,s>>>(p); break;
    case 5: gemm_gl<5,false,false><<<g,b,0,s>>>(p); break;
  }
}

static void run_gl_part(hipStream_t s, const GemmM& p, int nb) {
  dim3 g((p.N + 63)/64, (p.M + 63)/64, nb * p.nSplit), b(256, 1, 1);
  gemm_gl<0,true,false><<<g,b,0,s>>>(p);
}

static void run_pv(hipStream_t s, const GemmM& p, int nb) {
  dim3 g((p.N + 63)/64, (p.M + 63)/64, nb), b(256, 1, 1);
  gemm_mfma<0,true><<<g,b,0,s>>>(p);
}

// ------------------------------------------------------------- split-K reduce
__global__ __launch_bounds__(256) void reduce_epi4(
    const float* __restrict__ part, long partStride, int S,
    float* __restrict__ C, const float* __restrict__ E,
    int Mv, int Nv, int ldc, long sC0, int ldE, int total) {
  int idx = blockIdx.x*256 + threadIdx.x;
  if (idx >= total) return;
  int n = idx % Nv;
  int m = (idx / Nv) % Mv;
  int b0 = idx / (Nv * Mv);
  long co = b0*sC0 + (long)m*ldc + n;
  float v = 0.f;
  for (int s = 0; s < S; ++s) v += part[(long)s*partStride + co];
  v += E[(long)m*ldE + n];
  C[co] = v;
}

// ------------------------------------------------------ fp32 -> bf16 convert
__global__ __launch_bounds__(256) void cvt2_bf16(const float* __restrict__ src,
                                                 short* __restrict__ dst, int n8,
                                                 long srcStride, long dstStride, int total8) {
  int i = blockIdx.x*256 + threadIdx.x;
  if (i >= total8) return;
  int l = i / n8, j = i % n8;
  const float* s = src + srcStride*l + (long)8*j;
  short* d = dst + dstStride*l + (long)8*j;
  float4 a = *(const float4*)s;
  float4 b = *(const float4*)(s + 4);
  short8 o;
  o[0]=f2bf(a.x); o[1]=f2bf(a.y); o[2]=f2bf(a.z); o[3]=f2bf(a.w);
  o[4]=f2bf(b.x); o[5]=f2bf(b.y); o[6]=f2bf(b.z); o[7]=f2bf(b.w);
  *(short8*)d = o;
}

static void cvtT(hipStream_t s, const float* src, short* dst, long nPerLayer,
                 long srcStride, long dstStride, int L) {
  int n8 = (int)(nPerLayer / 8);
  int total8 = n8 * L;
  cvt2_bf16<<<dim3((total8 + 255)/256), dim3(256), 0, s>>>(src, dst, n8, srcStride, dstStride, total8);
}

// ================================================================ skinny GEMV4
template<int EPI>
__global__ __launch_bounds__(256) void gemv4(const float* __restrict__ A,
                                             const float* __restrict__ B,
                                             float* __restrict__ C,
                                             const float* __restrict__ bias,
                                             int N, int K, int ldc) {
  int wave = threadIdx.x >> 6, lane = threadIdx.x & 63;
  int n = blockIdx.x * 4 + wave;
  if (n >= N) return;
  const float* Brow = B + (long)n * K;
  float acc0 = 0.f, acc1 = 0.f, acc2 = 0.f, acc3 = 0.f;
  for (int k = lane * 4; k < K; k += 256) {
    float4 b = *(const float4*)(Brow + k);
    float4 a0 = *(const float4*)(A + 0*K + k);
    float4 a1 = *(const float4*)(A + 1*K + k);
    float4 a2 = *(const float4*)(A + 2*K + k);
    float4 a3 = *(const float4*)(A + 3*K + k);
    acc0 += a0.x*b.x + a0.y*b.y + a0.z*b.z + a0.w*b.w;
    acc1 += a1.x*b.x + a1.y*b.y + a1.z*b.z + a1.w*b.w;
    acc2 += a2.x*b.x + a2.y*b.y + a2.z*b.z + a2.w*b.w;
    acc3 += a3.x*b.x + a3.y*b.y + a3.z*b.z + a3.w*b.w;
  }
#pragma unroll
  for (int off = 32; off; off >>= 1) {
    acc0 += __shfl_xor(acc0, off);
    acc1 += __shfl_xor(acc1, off);
    acc2 += __shfl_xor(acc2, off);
    acc3 += __shfl_xor(acc3, off);
  }
  if (lane == 0) {
    float bs = bias[n];
    float v[4] = {acc0 + bs, acc1 + bs, acc2 + bs, acc3 + bs};
#pragma unroll
    for (int m = 0; m < 4; ++m) {
      float x = v[m];
      if (EPI == 2) x = x / (1.f + expf(-x));
      C[(long)m * ldc + n] = x;
    }
  }
}

// ---------------------------------------------------------------- small kernels
__global__ void embed_text_cls(const float* __restrict__ Wtok, const int* __restrict__ toks,
                               const float* __restrict__ pos_text, const float* __restrict__ cls_tok,
                               float* __restrict__ x) {
  int idx = blockIdx.x*256 + threadIdx.x;           // over B*65*DIM
  int d = idx % kDim;
  int t = (idx / kDim) % (kText + 1);
  int b = idx / (kDim * (kText + 1));
  float v;
  if (t < kText) {
    int tok = toks[b*kText + t];
    v = Wtok[(long)d*kVocab + tok] + pos_text[(long)t*kDim + d];
  } else {
    v = cls_tok[d];
  }
  x[((long)b*kTok + t)*kDim + d] = v;
}

__global__ void extract_patches(const float* __restrict__ img, short* __restrict__ pat) {
  int idx = blockIdx.x*256 + threadIdx.x;           // B*256*768
  int k = idx % 768;
  int p = (idx/768) % kNp;
  int b = idx/(768*kNp);
  int c = k >> 8, py = (k >> 4) & 15, px = k & 15;
  int hp = p >> 4, wp = p & 15;
  pat[idx] = f2bf(img[(((long)(b*3 + c))*kImg + hp*16 + py)*kImg + wp*16 + px]);
}

__global__ void time_freqs(const int* __restrict__ ts, float* __restrict__ temb) {
  int b = blockIdx.x, i = threadIdx.x;              // 128 threads
  float f = expf(-9.210340371976184f * (float)i / 128.f);
  float a = (float)ts[b] * f;
  temb[b*kTdim + i] = cosf(a);
  temb[b*kTdim + 128 + i] = sinf(a);
}

__global__ void silu_kernel(const float* __restrict__ in, float* __restrict__ outp, int n) {
  int i = blockIdx.x*256 + threadIdx.x;
  if (i < n) { float x = in[i]; outp[i] = x / (1.f + expf(-x)); }
}

__device__ __forceinline__ float block_sum(float v) {
  __shared__ float sh[4];
  for (int off = 32; off; off >>= 1) v += __shfl_down(v, off);
  if ((threadIdx.x & 63) == 0) sh[threadIdx.x >> 6] = v;
  __syncthreads();
  float s = sh[0] + sh[1] + sh[2] + sh[3];
  __syncthreads();
  return s;
}

__global__ __launch_bounds__(256) void ln_mod_kernel(
    const float* __restrict__ x, const float* __restrict__ g, const float* __restrict__ be,
    const float* __restrict__ mod, int shOff, int scOff, short* __restrict__ outp) {
  int row = blockIdx.x;                 // b*321 + t
  int b = row / kTok;
  const float* xr = x + (long)row*kDim;
  float s = 0.f, s2 = 0.f;
  for (int i = threadIdx.x; i < kDim; i += 256) { float v = xr[i]; s += v; s2 += v*v; }
  s = block_sum(s); s2 = block_sum(s2);
  float m = s / kDim;
  float inv = rsqrtf(s2 / kDim - m*m + kEps);
  const float* mb = mod + (long)b*(6*kDim);
  for (int i = threadIdx.x; i < kDim; i += 256) {
    float xn = (xr[i] - m)*inv*g[i] + be[i];
    outp[(long)row*kDim + i] = f2bf(xn*(1.f + mb[scOff + i]) + mb[shOff + i]);
  }
}

// fused: x_new = x_old + gate * sum_s part ; then LN+mod -> bf16, and write x_new
__global__ __launch_bounds__(256) void ln_mod_red_kernel(
    const float* __restrict__ xin, const float* __restrict__ part, long pStride, int S,
    const float* __restrict__ gate, const float* __restrict__ g, const float* __restrict__ be,
    const float* __restrict__ mod, int shOff, int scOff,
    float* __restrict__ xout, short* __restrict__ outp) {
  int row = blockIdx.x;                 // b*321 + t
  int b = row / kTok;
  long base = (long)row*kDim;
  const float* gt = gate + (long)b*(6*kDim);
  float v[4];
  float s = 0.f, s2 = 0.f;
#pragma unroll
  for (int c = 0; c < 4; ++c) {
    int i = threadIdx.x + 256*c;
    float acc = 0.f;
    for (int sp = 0; sp < S; ++sp) acc += part[(long)sp*pStride + base + i];
    float xv = xin[base + i] + gt[i] * acc;
    v[c] = xv; s += xv; s2 += xv*xv;
  }
  s = block_sum(s); s2 = block_sum(s2);
  float m = s / kDim;
  float inv = rsqrtf(s2 / kDim - m*m + kEps);
  const float* mb = mod + (long)b*(6*kDim);
#pragma unroll
  for (int c = 0; c < 4; ++c) {
    int i = threadIdx.x + 256*c;
    xout[base + i] = v[c];
    float xn = (v[c] - m)*inv*g[i] + be[i];
    outp[base + i] = f2bf(xn*(1.f + mb[scOff + i]) + mb[shOff + i]);
  }
}

__global__ __launch_bounds__(256) void final_ln_kernel(
    const float* __restrict__ x, const float* __restrict__ g, const float* __restrict__ be,
    short* __restrict__ yn) {
  int row = blockIdx.x;                 // b*256 + p
  int b = row / kNp, p = row % kNp;
  const float* xr = x + ((long)(b*kTok + kText + 1 + p))*kDim;
  float s = 0.f, s2 = 0.f;
  for (int i = threadIdx.x; i < kDim; i += 256) { float v = xr[i]; s += v; s2 += v*v; }
  s = block_sum(s); s2 = block_sum(s2);
  float m = s / kDim;
  float inv = rsqrtf(s2 / kDim - m*m + kEps);
  for (int i = threadIdx.x; i < kDim; i += 256)
    yn[(long)row*kDim + i] = f2bf((xr[i] - m)*inv*g[i] + be[i]);
}

// fused MLP2-reduce + final LN (img rows only; x not persisted)
__global__ __launch_bounds__(256) void final_ln_red_kernel(
    const float* __restrict__ xin, const float* __restrict__ part, long pStride, int S,
    const float* __restrict__ gate, const float* __restrict__ g, const float* __restrict__ be,
    short* __restrict__ yn) {
  int row = blockIdx.x;                 // b*256 + p
  int b = row / kNp, p = row % kNp;
  long xb = ((long)(b*kTok + kText + 1 + p))*kDim;
  const float* gt = gate + (long)b*(6*kDim);
  float v[4];
  float s = 0.f, s2 = 0.f;
#pragma unroll
  for (int c = 0; c < 4; ++c) {
    int i = threadIdx.x + 256*c;
    float acc = 0.f;
    for (int sp = 0; sp < S; ++sp) acc += part[(long)sp*pStride + xb + i];
    float xv = xin[xb + i] + gt[i] * acc;
    v[c] = xv; s += xv; s2 += xv*xv;
  }
  s = block_sum(s); s2 = block_sum(s2);
  float m = s / kDim;
  float inv = rsqrtf(s2 / kDim - m*m + kEps);
#pragma unroll
  for (int c = 0; c < 4; ++c) {
    int i = threadIdx.x + 256*c;
    yn[(long)row*kDim + i] = f2bf((v[c] - m)*inv*g[i] + be[i]);
  }
}

// RoPE: read fused fp32 QKV [row][3072], write bf16 q,k [row][1024]
__global__ __launch_bounds__(256) void rope_bf16(const float* __restrict__ qkv,
                                                 short* __restrict__ qb,
                                                 short* __restrict__ kb) {
  int idx = blockIdx.x*256 + threadIdx.x;          // B*321*1024
  int d = idx & (kDim - 1);
  int r = idx >> 10;
  int n = r % kTok;
  int hd = d & 63;
  int j = hd & 31;
  float inv = expf(-9.210340371976184f * (float)j / 32.f);
  float ang = (float)n * inv;
  float c = cosf(ang), s = sinf(ang);
  const float* row = qkv + (long)r * (3*kDim);
  int base = d - hd;
  float qv = row[d], kv = row[kDim + d];
  float qr, kr;
  if (hd < 32) { qr = -row[base + 2*hd + 1];      kr = -row[kDim + base + 2*hd + 1]; }
  else         { qr =  row[base + 2*(hd - 32)];   kr =  row[kDim + base + 2*(hd - 32)]; }
  qb[idx] = f2bf(qv*c + qr*s);
  kb[idx] = f2bf(kv*c + kr*s);
}

// V slice of fused QKV -> vtb[b][h][hd][tok(pad 328)] bf16 (pad zeros)
__global__ __launch_bounds__(256) void vtrans_kernel(const float* __restrict__ qkv,
                                                     short* __restrict__ vtb) {
  int idx = blockIdx.x*256 + threadIdx.x;          // B*16*64*328
  int tok = idx % kScLd;
  int hd  = (idx / kScLd) % kHd;
  int h   = (idx / (kScLd*kHd)) % kHeads;
  int b   = idx / (kScLd*kHd*kHeads);
  float v = 0.f;
  if (tok < kTok) v = qkv[((long)(b*kTok + tok))*(3*kDim) + 2*kDim + h*kHd + hd];
  vtb[idx] = f2bf(v);
}

// 4 rows per block (one per wave)
__global__ __launch_bounds__(256) void softmax_rows4(float* __restrict__ sc,
                                                     short* __restrict__ dst, int nRows) {
  int wid = threadIdx.x >> 6, t = threadIdx.x & 63;
  int row = blockIdx.x*4 + wid;
  if (row >= nRows) return;
  float* r = sc + (long)row*kScLd;
  short* d = dst + (long)row*kScLd;
  float mx = -1e30f;
  for (int i = t; i < kTok; i += 64) mx = fmaxf(mx, r[i]);
  for (int off = 32; off; off >>= 1) mx = fmaxf(mx, __shfl_xor(mx, off));
  float sum = 0.f;
  for (int i = t; i < kTok; i += 64) { float e = expf(r[i] - mx); r[i] = e; sum += e; }
  for (int off = 32; off; off >>= 1) sum += __shfl_xor(sum, off);
  float invs = 1.f / sum;
  for (int i = t; i < kTok; i += 64) d[i] = f2bf(r[i] * invs);
}

__global__ void unpatchify(const float* __restrict__ op, float* __restrict__ outp) {
  int idx = blockIdx.x*256 + threadIdx.x;           // B*3*256*256
  int w = idx & 255;
  int h = (idx >> 8) & 255;
  int c = (idx >> 16) % 3;
  int b = idx / (3 * kImg * kImg);
  int hp = h >> 4, py = h & 15, wp = w >> 4, px = w & 15;
  outp[idx] = op[((long)(b*kNp + hp*16 + wp))*768 + c*256 + py*16 + px];
}

// fused: final split-K reduce + bias + unpatchify, direct to output
__global__ void unpatchify_red(const float* __restrict__ part, long pStride, int S,
                               const float* __restrict__ bias, float* __restrict__ outp) {
  int idx = blockIdx.x*256 + threadIdx.x;           // B*3*256*256
  int w = idx & 255;
  int h = (idx >> 8) & 255;
  int c = (idx >> 16) % 3;
  int b = idx / (3 * kImg * kImg);
  int hp = h >> 4, py = h & 15, wp = w >> 4, px = w & 15;
  long co = ((long)(b*kNp + hp*16 + wp))*768 + c*256 + py*16 + px;
  float v = bias[c*256 + py*16 + px];
  for (int s = 0; s < S; ++s) v += part[(long)s*pStride + co];
  outp[idx] = v;
}

// ---------------------------------------------------------------- launch
extern "C" void kernel_launch(void* const* d_in, const int* in_sizes, int n_in,
                              void* d_out, int out_size, void* d_ws, size_t ws_size,
                              hipStream_t stream) {
  (void)in_sizes; (void)n_in; (void)out_size;
  const float* noisy    = (const float*)d_in[0];
  const int*   toks     = (const int*)d_in[1];
  const int*   tsteps   = (const int*)d_in[2];
  const float* W_tok    = (const float*)d_in[3];
  const float* pos_text = (const float*)d_in[4];
  const float* W_patch  = (const float*)d_in[5];
  const float* pos_img  = (const float*)d_in[6];
  const float* cls_tok  = (const float*)d_in[7];
  const float* W_t1     = (const float*)d_in[8];
  const float* b_t1     = (const float*)d_in[9];
  const float* W_t2     = (const float*)d_in[10];
  const float* b_t2     = (const float*)d_in[11];
  const float* ln1_g    = (const float*)d_in[12];
  const float* ln1_b    = (const float*)d_in[13];
  const float* Wq       = (const float*)d_in[14];
  const float* Wk       = (const float*)d_in[15];
  const float* Wv       = (const float*)d_in[16];
  const float* Wo       = (const float*)d_in[17];
  const float* ln2_g    = (const float*)d_in[18];
  const float* ln2_b    = (const float*)d_in[19];
  const float* Wm1      = (const float*)d_in[20];
  const float* Wm2      = (const float*)d_in[21];
  const float* Wada     = (const float*)d_in[22];
  const float* b_ada    = (const float*)d_in[23];
  const float* fn_g     = (const float*)d_in[24];
  const float* fn_b     = (const float*)d_in[25];
  const float* W_final  = (const float*)d_in[26];
  const float* b_final  = (const float*)d_in[27];
  float* out = (float*)d_out;

  float* ws = (float*)d_ws;
  auto alloc = [&](long nf) { float* r = ws; ws += nf; return r; };

  const long seqSz = (long)kBn * kTok * kDim;            // 1,314,816
  float* x    = alloc(seqSz);
  float* qkv  = alloc((long)kBn*kTok*3*kDim);
  float* sc   = alloc((long)kBn*kHeads*kTok*kScLd);
  short* xnb  = (short*)alloc(seqSz/2);
  short* qb   = (short*)alloc(seqSz/2);
  short* kb   = (short*)alloc(seqSz/2);
  short* ob   = (short*)alloc(seqSz/2);
  short* vtb  = (short*)alloc((long)kBn*kHeads*kHd*kScLd/2);
  short* scb  = (short*)alloc((long)kBn*kHeads*kTok*kScLd/2);
  short* patb = (short*)alloc((long)kBn*kNp*768/2);
  short* ynb  = (short*)alloc((long)kBn*kNp*kDim/2);
  float* temb = alloc(kBn*kTdim);
  float* t1   = alloc(kBn*kDim);
  float* temb2= alloc(kBn*kDim);
  float* st   = alloc(kBn*kDim);
  float* mod  = alloc(2L*kBn*6*kDim);
  short* hb   = (short*)sc;       // MLP hidden aliases scores
  float* outp = qkv;              // fallback final out aliases qkv

  // bf16 weight arena
  const long oPatch = 0;
  const long nPatch = (long)kDim*768;                    // 786,432
  const long perLayer = 3L*kDim*kDim + (long)kDim*kDim + 2L*kMlp*kDim;  // 12,582,912
  const long oLayer = nPatch;
  const long oFinal = nPatch + 2*perLayer;
  const long nFinal = (long)768*kDim;
  short* wAr = (short*)alloc((nPatch + 2*perLayer + nFinal)/2);

  const long scrStride = seqSz;
  float* scr = alloc(4*scrStride);
  bool split_ok = ((char*)ws - (char*)d_ws) <= (long)ws_size;

  // --- weight conversions (bf16 arena), 8 dispatches up front
  cvtT(stream, W_patch, wAr + oPatch, nPatch, 0, 0, 1);
  cvtT(stream, Wq,  wAr + oLayer + 0,               (long)kDim*kDim, (long)kDim*kDim, perLayer, 2);
  cvtT(stream, Wk,  wAr + oLayer + (long)kDim*kDim, (long)kDim*kDim, (long)kDim*kDim, perLayer, 2);
  cvtT(stream, Wv,  wAr + oLayer + 2L*kDim*kDim,    (long)kDim*kDim, (long)kDim*kDim, perLayer, 2);
  cvtT(stream, Wo,  wAr + oLayer + 3L*kDim*kDim,    (long)kDim*kDim, (long)kDim*kDim, perLayer, 2);
  cvtT(stream, Wm1, wAr + oLayer + 4L*kDim*kDim,    (long)kMlp*kDim, (long)kMlp*kDim, perLayer, 2);
  cvtT(stream, Wm2, wAr + oLayer + 4L*kDim*kDim + (long)kMlp*kDim,
       (long)kMlp*kDim, (long)kMlp*kDim, perLayer, 2);
  cvtT(stream, W_final, wAr + oFinal, nFinal, 0, 0, 1);

  // --- embeddings
  embed_text_cls<<<(kBn*(kText+1)*kDim)/256, 256, 0, stream>>>(W_tok, toks, pos_text, cls_tok, x);
  extract_patches<<<(kBn*kNp*768)/256, 256, 0, stream>>>(noisy, patb);
  {
    GemmM p = mkm(patb, wAr + oPatch, split_ok ? scr : (x + (kText+1)*kDim),
                  kNp, kDim, 768, 768, 768, kDim);
    p.sA0 = (long)kNp*768; p.sC0 = (long)kTok*kDim;
    if (split_ok) {
      p.nSplit = 3; p.splitLen = 256; p.partStride = scrStride;
      run_gl_part(stream, p, kBn);
      int total = kBn*kNp*kDim;
      reduce_epi4<<<(total+255)/256, 256, 0, stream>>>(scr, scrStride, 3,
          x + (kText+1)*kDim, pos_img, kNp, kDim, kDim, (long)kTok*kDim, kDim, total);
    } else {
      p.E = pos_img; p.ldE = kDim;
      run_gl(stream, 4, false, p, kBn);
    }
  }
  // --- time embedding + modulation (all upfront)
  time_freqs<<<kBn, 128, 0, stream>>>(tsteps, temb);
  gemv4<2><<<kDim/4, 256, 0, stream>>>(temb, W_t1, t1, b_t1, kDim, kTdim, kDim);
  gemv4<1><<<kDim/4, 256, 0, stream>>>(t1, W_t2, temb2, b_t2, kDim, kDim, kDim);
  silu_kernel<<<(kBn*kDim + 255)/256, 256, 0, stream>>>(temb2, st, kBn*kDim);
  for (int l = 0; l < 2; ++l)
    gemv4<1><<<(6*kDim)/4, 256, 0, stream>>>(st, Wada + (long)l*6*kDim*kDim,
                                             mod + (long)l*kBn*6*kDim,
                                             b_ada + (long)l*6*kDim, 6*kDim, kDim, 6*kDim);

  // first LN (x complete after patch reduce)
  ln_mod_kernel<<<kBn*kTok, 256, 0, stream>>>(x, ln1_g, ln1_b, mod, 0, kDim, xnb);

  for (int l = 0; l < 2; ++l) {
    const short* wqkv_l = wAr + oLayer + (long)l*perLayer;
    const short* wo_l   = wqkv_l + 3L*kDim*kDim;
    const short* wm1_l  = wqkv_l + 4L*kDim*kDim;
    const short* wm2_l  = wm1_l + (long)kMlp*kDim;
    float* mod_l = mod + (long)l*kBn*6*kDim;

    { // fused QKV projection -> qkv fp32
      GemmM p = mkm(xnb, wqkv_l, qkv, kBn*kTok, 3*kDim, kDim, kDim, kDim, 3*kDim);
      run_gl(stream, 0, false, p, 1);
    }
    rope_bf16<<<(int)(seqSz/256), 256, 0, stream>>>(qkv, qb, kb);
    vtrans_kernel<<<(kBn*kHeads*kHd*kScLd)/256, 256, 0, stream>>>(qkv, vtb);

    { // scores = 0.125 * q @ k^T per (b,h)
      GemmM p = mkm(qb, kb, sc, kTok, kTok, kHd, kDim, kDim, kScLd);
      p.sA0 = (long)kTok*kDim; p.sA1 = kHd;
      p.sB0 = (long)kTok*kDim; p.sB1 = kHd;
      p.sC0 = (long)kHeads*kTok*kScLd; p.sC1 = (long)kTok*kScLd;
      p.innerB = kHeads; p.alpha = 0.125f;
      run_gl(stream, 0, false, p, kBn*kHeads);
    }
    {
      int nRows = kBn*kHeads*kTok;
      softmax_rows4<<<(nRows+3)/4, 256, 0, stream>>>(sc, scb, nRows);
    }
    { // o = P @ V per (b,h), bf16 out  (K=321 -> guarded kernel)
      GemmM p = mkm(scb, vtb, (float*)ob, kTok, kHd, kTok, kScLd, kScLd, kDim);
      p.sA0 = (long)kHeads*kTok*kScLd; p.sA1 = (long)kTok*kScLd;
      p.sB0 = (long)kHeads*kHd*kScLd;  p.sB1 = (long)kHd*kScLd;
      p.sC0 = (long)kTok*kDim;         p.sC1 = kHd;
      p.innerB = kHeads;
      run_pv(stream, p, kBn*kHeads);
    }
    { // o @ Wo^T
      GemmM p = mkm(ob, wo_l, split_ok ? scr : x, kBn*kTok, kDim, kDim, kDim, kDim, kDim);
      if (split_ok) {
        p.nSplit = 4; p.splitLen = 256; p.partStride = scrStride;
        run_gl_part(stream, p, 1);
        // fused: reduce + gated residual + LN2+mod
        ln_mod_red_kernel<<<kBn*kTok, 256, 0, stream>>>(x, scr, scrStride, 4,
            mod_l + 2*kDim, ln2_g + l*kDim, ln2_b + l*kDim, mod_l, 3*kDim, 4*kDim, x, xnb);
      } else {
        p.E = mod_l + 2*kDim; p.ldE = 6*kDim; p.rowsPB = kTok;
        run_gl(stream, 5, false, p, 1);
        ln_mod_kernel<<<kBn*kTok, 256, 0, stream>>>(x, ln2_g + l*kDim, ln2_b + l*kDim,
                                                    mod_l, 3*kDim, 4*kDim, xnb);
      }
    }
    { // MLP1 + gelu, bf16 hidden
      GemmM p = mkm(xnb, wm1_l, (float*)hb, kBn*kTok, kMlp, kDim, kDim, kDim, kMlp);
      run_gl(stream, 3, true, p, 1);
    }
    { // MLP2
      GemmM p = mkm(hb, wm2_l, split_ok ? scr : x, kBn*kTok, kDim, kMlp, kMlp, kMlp, kDim);
      if (split_ok) {
        p.nSplit = 4; p.splitLen = 1024; p.partStride = scrStride;
        run_gl_part(stream, p, 1);
        if (l == 0) {
          // fused: reduce + gated residual + LN1(layer1)+mod1
          ln_mod_red_kernel<<<kBn*kTok, 256, 0, stream>>>(x, scr, scrStride, 4,
              mod_l + 5*kDim, ln1_g + kDim, ln1_b + kDim,
              mod + (long)kBn*6*kDim, 0, kDim, x, xnb);
        } else {
          // fused: reduce + gated residual + final LN
          final_ln_red_kernel<<<kBn*kNp, 256, 0, stream>>>(x, scr, scrStride, 4,
              mod_l + 5*kDim, fn_g, fn_b, ynb);
        }
      } else {
        p.E = mod_l + 5*kDim; p.ldE = 6*kDim; p.rowsPB = kTok;
        run_gl(stream, 5, false, p, 1);
        if (l == 0)
          ln_mod_kernel<<<kBn*kTok, 256, 0, stream>>>(x, ln1_g + kDim, ln1_b + kDim,
                                                      mod + (long)kBn*6*kDim, 0, kDim, xnb);
        else
          final_ln_kernel<<<kBn*kNp, 256, 0, stream>>>(x, fn_g, fn_b, ynb);
      }
    }
  }

  { // final projection
    GemmM p = mkm(ynb, wAr + oFinal, split_ok ? scr : outp, kBn*kNp, 768, kDim, kDim, kDim, 768);
    if (split_ok) {
      p.nSplit = 4; p.splitLen = 256; p.partStride = (long)kBn*kNp*768;
      run_gl_part(stream, p, 1);
      unpatchify_red<<<(kBn*3*kImg*kImg)/256, 256, 0, stream>>>(scr, (long)kBn*kNp*768, 4,
                                                                b_final, out);
    } else {
      p.E = b_final;
      run_gl(stream, 1, false, p, 1);
      unpatchify<<<(kBn*3*kImg*kImg)/256, 256, 0, stream>>>(outp, out);
    }
  }
}

// Round 4
// 786.597 us; speedup vs baseline: 1.1103x; 1.0050x over previous
//
#include <hip/hip_runtime.h>
#include <math.h>

constexpr int kBn    = 4;
constexpr int kText  = 64;
constexpr int kImg   = 256;
constexpr int kDim   = 1024;
constexpr int kHeads = 16;
constexpr int kHd    = 64;
constexpr int kNp    = 256;    // patches
constexpr int kTok   = 321;    // 64 text + 1 cls + 256 img
constexpr int kVocab = 50000;
constexpr int kTdim  = 256;
constexpr int kMlp   = 4096;
constexpr int kScLd  = 384;    // score row stride (321 padded to mult of 64 for glds PV)
constexpr int kScRow = 384;    // score rows allocated per (b,h) (M-tile overreach safe)
constexpr float kEps = 1e-5f;

typedef __attribute__((ext_vector_type(8))) short short8;
typedef __attribute__((ext_vector_type(4))) float f32x4;

// RNE float -> bf16 bits
__device__ __forceinline__ short f2bf(float x) {
  unsigned u = __builtin_bit_cast(unsigned, x);
  unsigned r = (u + 0x7FFFu + ((u >> 16) & 1u)) >> 16;
  return (short)r;
}

// async global->LDS, 16B per lane, dest = base + lane*16 (wave-uniform base)
__device__ __forceinline__ void glds16(const short* g, short* l) {
  __builtin_amdgcn_global_load_lds(
      (const __attribute__((address_space(1))) unsigned int*)g,
      (__attribute__((address_space(3))) unsigned int*)l, 16, 0, 0);
}

// =================================================================== MFMA GEMM
// C[m][n] = alpha * sum_k A[m][k] * B[n][k]   (A,B bf16 in memory, fp32 accum)
// EPI: 0 none | 1 +bias[n] | 3 gelu | 4 +E[m][n] | 5 gated residual
struct GemmM {
  const short* A; const short* B; float* C; const float* E;
  int M, N, K, lda, ldb, ldc;
  long sA0, sA1, sB0, sB1, sC0, sC1;
  int innerB, ldE, rowsPB;
  float alpha;
  int nSplit, splitLen;
  long partStride;
};

__device__ __forceinline__ float epi_apply(int EPI, const GemmM& p, const float* E,
                                           long co, int gm, int gn, float v) {
  if (EPI == 1) v += E[gn];
  else if (EPI == 3) v = 0.5f*v*(1.f + erff(v*0.70710678118654752f));
  else if (EPI == 4) v += E[(long)gm*p.ldE + gn];
  else if (EPI == 5) v = p.C[co] + E[(long)(gm / p.rowsPB)*p.ldE + gn] * v;
  return v;
}

// ------------------- 64x64 tile, global_load_lds staging (requires K%64==0) --
// LDS: linear [64 rows][128B], content XOR-swizzled: LDS[r][c16] = G[r][c16^(r&7)]
// No load guards: M/N edge rows read in-workspace garbage, dropped by store guard.
template<int EPI, bool PART, bool OUTBF>
__global__ __launch_bounds__(256) void gemm_gl(GemmM p) {
  int bz = blockIdx.z;
  int split = 0;
  if (PART) { split = bz % p.nSplit; bz /= p.nSplit; }
  int b1 = bz % p.innerB, b0 = bz / p.innerB;
  const short* A = p.A + b0*p.sA0 + b1*p.sA1;
  const short* B = p.B + b0*p.sB0 + b1*p.sB1;
  long cbase = b0*p.sC0 + b1*p.sC1 + (PART ? (long)split * p.partStride : 0);
  const float* E = p.E;

  int kBeg = PART ? split * p.splitLen : 0;
  int kEnd = PART ? min(p.K, kBeg + p.splitLen) : p.K;

  __shared__ short As[2][64*64];
  __shared__ short Bs[2][64*64];

  int tid  = threadIdx.x;
  int lane = tid & 63, widx = tid >> 6;
  int quad = lane >> 4, ln = lane & 15;
  int wm = (widx >> 1) * 32, wn = (widx & 1) * 32;
  int n0 = blockIdx.x * 64, m0 = blockIdx.y * 64;

  int l3 = lane >> 3, l7 = lane & 7;
  int kofs = (l7 ^ l3) * 8;                       // pre-swizzled element offset
  const short* gA0 = A + (long)(m0 + 16*widx + l3) * p.lda + kofs;
  const short* gA1 = gA0 + (long)8 * p.lda;
  const short* gB0 = B + (long)(n0 + 16*widx + l3) * p.ldb + kofs;
  const short* gB1 = gB0 + (long)8 * p.ldb;
  short* lA0 = &As[0][(2*widx)*512];
  short* lA1 = &As[0][(2*widx+1)*512];
  short* lB0 = &Bs[0][(2*widx)*512];
  short* lB1 = &Bs[0][(2*widx+1)*512];

  auto stage = [&](int buf, int k0) {
    int bo = buf * 4096;
    glds16(gA0 + k0, lA0 + bo);
    glds16(gA1 + k0, lA1 + bo);
    glds16(gB0 + k0, lB0 + bo);
    glds16(gB1 + k0, lB1 + bo);
  };

  f32x4 zero = {0.f, 0.f, 0.f, 0.f};
  f32x4 acc[2][2];
  acc[0][0] = zero; acc[0][1] = zero; acc[1][0] = zero; acc[1][1] = zero;

  stage(0, kBeg);
  int buf = 0;
  for (int k0 = kBeg; k0 < kEnd; k0 += 64) {
    if (k0 + 64 < kEnd) stage(buf ^ 1, k0 + 64);
    __syncthreads();                 // drains vmcnt -> buf ready
    const char* Ab = (const char*)&As[buf][0];
    const char* Bb = (const char*)&Bs[buf][0];
#pragma unroll
    for (int ks = 0; ks < 2; ++ks) {
      int cb = ks*64 + quad*16;
      int r0 = wm + ln, r1 = wm + 16 + ln, r2 = wn + ln, r3 = wn + 16 + ln;
      short8 a0 = *(const short8*)(Ab + r0*128 + (cb ^ ((r0 & 7) << 4)));
      short8 a1 = *(const short8*)(Ab + r1*128 + (cb ^ ((r1 & 7) << 4)));
      short8 b0 = *(const short8*)(Bb + r2*128 + (cb ^ ((r2 & 7) << 4)));
      short8 b1 = *(const short8*)(Bb + r3*128 + (cb ^ ((r3 & 7) << 4)));
      acc[0][0] = __builtin_amdgcn_mfma_f32_16x16x32_bf16(a0, b0, acc[0][0], 0, 0, 0);
      acc[0][1] = __builtin_amdgcn_mfma_f32_16x16x32_bf16(a0, b1, acc[0][1], 0, 0, 0);
      acc[1][0] = __builtin_amdgcn_mfma_f32_16x16x32_bf16(a1, b0, acc[1][0], 0, 0, 0);
      acc[1][1] = __builtin_amdgcn_mfma_f32_16x16x32_bf16(a1, b1, acc[1][1], 0, 0, 0);
    }
    __syncthreads();
    buf ^= 1;
  }

  // C/D layout: col = lane&15, row = quad*4 + reg  [verified m89/m91]
#pragma unroll
  for (int mi = 0; mi < 2; ++mi)
#pragma unroll
    for (int ni = 0; ni < 2; ++ni)
#pragma unroll
      for (int reg = 0; reg < 4; ++reg) {
        int gm = m0 + wm + mi*16 + quad*4 + reg;
        int gn = n0 + wn + ni*16 + ln;
        if (gm >= p.M || gn >= p.N) continue;
        long co = cbase + (long)gm * p.ldc + gn;
        float v = acc[mi][ni][reg] * p.alpha;
        if (!PART) v = epi_apply(EPI, p, E, co, gm, gn, v);
        if (OUTBF) ((short*)p.C)[co] = f2bf(v);
        else       p.C[co] = v;
      }
}

// ------------------- 64M x 128N tile, glds staging (big GEMMs, K%64==0) -----
// 4 waves; each wave owns 64x32 (acc[4][2]): 6 ds_read feed 8 MFMA per half-step.
template<int EPI, bool PART, bool OUTBF>
__global__ __launch_bounds__(256) void gemm_gl_n128(GemmM p) {
  int bz = blockIdx.z;
  int split = 0;
  if (PART) { split = bz % p.nSplit; bz /= p.nSplit; }
  int b1 = bz % p.innerB, b0 = bz / p.innerB;
  const short* A = p.A + b0*p.sA0 + b1*p.sA1;
  const short* B = p.B + b0*p.sB0 + b1*p.sB1;
  long cbase = b0*p.sC0 + b1*p.sC1 + (PART ? (long)split * p.partStride : 0);
  const float* E = p.E;

  int kBeg = PART ? split * p.splitLen : 0;
  int kEnd = PART ? min(p.K, kBeg + p.splitLen) : p.K;

  __shared__ short As[2][64*64];    // 64 rows x 128B
  __shared__ short Bs[2][128*64];   // 128 rows x 128B

  int tid  = threadIdx.x;
  int lane = tid & 63, widx = tid >> 6;
  int quad = lane >> 4, ln = lane & 15;
  int n0 = blockIdx.x * 128, m0 = blockIdx.y * 64;

  int l3 = lane >> 3, l7 = lane & 7;
  int kofs = (l7 ^ l3) * 8;
  const short* gA0 = A + (long)(m0 + 16*widx + l3) * p.lda + kofs;
  const short* gA1 = gA0 + (long)8 * p.lda;
  const short* gB0 = B + (long)(n0 + 32*widx + l3) * p.ldb + kofs;
  const long ldb8 = (long)8 * p.ldb;
  short* lA = &As[0][(2*widx)*512];
  short* lB = &Bs[0][(4*widx)*512];

  auto stage = [&](int buf, int k0) {
    int boA = buf * 4096, boB = buf * 8192;
    glds16(gA0 + k0, lA + boA);
    glds16(gA1 + k0, lA + 512 + boA);
    glds16(gB0 + k0,            lB + boB);
    glds16(gB0 + ldb8 + k0,     lB + 512 + boB);
    glds16(gB0 + 2*ldb8 + k0,   lB + 1024 + boB);
    glds16(gB0 + 3*ldb8 + k0,   lB + 1536 + boB);
  };

  f32x4 zero = {0.f, 0.f, 0.f, 0.f};
  f32x4 acc[4][2];
#pragma unroll
  for (int i = 0; i < 4; ++i) { acc[i][0] = zero; acc[i][1] = zero; }

  stage(0, kBeg);
  int buf = 0;
  for (int k0 = kBeg; k0 < kEnd; k0 += 64) {
    if (k0 + 64 < kEnd) stage(buf ^ 1, k0 + 64);
    __syncthreads();
    const char* Ab = (const char*)&As[buf][0];
    const char* Bb = (const char*)&Bs[buf][0];
#pragma unroll
    for (int ks = 0; ks < 2; ++ks) {
      int cb = ks*64 + quad*16;
      short8 a[4], b[2];
#pragma unroll
      for (int mi = 0; mi < 4; ++mi) {
        int r = mi*16 + ln;
        a[mi] = *(const short8*)(Ab + r*128 + (cb ^ ((r & 7) << 4)));
      }
#pragma unroll
      for (int ni = 0; ni < 2; ++ni) {
        int r = 32*widx + ni*16 + ln;
        b[ni] = *(const short8*)(Bb + r*128 + (cb ^ ((r & 7) << 4)));
      }
#pragma unroll
      for (int mi = 0; mi < 4; ++mi)
#pragma unroll
        for (int ni = 0; ni < 2; ++ni)
          acc[mi][ni] = __builtin_amdgcn_mfma_f32_16x16x32_bf16(a[mi], b[ni], acc[mi][ni], 0, 0, 0);
    }
    __syncthreads();
    buf ^= 1;
  }

#pragma unroll
  for (int mi = 0; mi < 4; ++mi)
#pragma unroll
    for (int ni = 0; ni < 2; ++ni)
#pragma unroll
      for (int reg = 0; reg < 4; ++reg) {
        int gm = m0 + mi*16 + quad*4 + reg;
        int gn = n0 + 32*widx + ni*16 + ln;
        if (gm >= p.M || gn >= p.N) continue;
        long co = cbase + (long)gm * p.ldc + gn;
        float v = acc[mi][ni][reg] * p.alpha;
        if (!PART) v = epi_apply(EPI, p, E, co, gm, gn, v);
        if (OUTBF) ((short*)p.C)[co] = f2bf(v);
        else       p.C[co] = v;
      }
}

static GemmM mkm(const short* A, const short* B, float* C,
                 int M, int N, int K, int lda, int ldb, int ldc) {
  GemmM p; p.A = A; p.B = B; p.C = C; p.E = nullptr;
  p.M = M; p.N = N; p.K = K; p.lda = lda; p.ldb = ldb; p.ldc = ldc;
  p.sA0 = p.sA1 = p.sB0 = p.sB1 = p.sC0 = p.sC1 = 0;
  p.innerB = 1; p.ldE = 0; p.rowsPB = 1; p.alpha = 1.f;
  p.nSplit = 1; p.splitLen = 0; p.partStride = 0;
  return p;
}

static void run_gl(hipStream_t s, int epi, bool outbf, const GemmM& p, int nb) {
  dim3 g((p.N + 63)/64, (p.M + 63)/64, nb), b(256, 1, 1);
  if (outbf) {
    if (epi == 3) gemm_gl<3,false,true><<<g,b,0,s>>>(p);
    else          gemm_gl<0,false,true><<<g,b,0,s>>>(p);
    return;
  }
  switch (epi) {
    case 0: gemm_gl<0,false,false><<<g,b,0,s>>>(p); break;
    case 1: gemm_gl<1,false,false><<<g,b,0,s>>>(p); break;
    case 4: gemm_gl<4,false,false><<<g,b,0,s>>>(p); break;
    case 5: gemm_gl<5,false,false><<<g,b,0,s>>>(p); break;
  }
}

static void run_gl128(hipStream_t s, int epi, bool outbf, const GemmM& p, int nb) {
  dim3 g((p.N + 127)/128, (p.M + 63)/64, nb), b(256, 1, 1);
  if (outbf) {
    if (epi == 3) gemm_gl_n128<3,false,true><<<g,b,0,s>>>(p);
    else          gemm_gl_n128<0,false,true><<<g,b,0,s>>>(p);
    return;
  }
  switch (epi) {
    case 0: gemm_gl_n128<0,false,false><<<g,b,0,s>>>(p); break;
    case 1: gemm_gl_n128<1,false,false><<<g,b,0,s>>>(p); break;
    case 4: gemm_gl_n128<4,false,false><<<g,b,0,s>>>(p); break;
    case 5: gemm_gl_n128<5,false,false><<<g,b,0,s>>>(p); break;
  }
}

static void run_gl128_part(hipStream_t s, const GemmM& p, int nb) {
  dim3 g((p.N + 127)/128, (p.M + 63)/64, nb * p.nSplit), b(256, 1, 1);
  gemm_gl_n128<0,true,false><<<g,b,0,s>>>(p);
}

// ------------------------------------------------------------- split-K reduce
__global__ __launch_bounds__(256) void reduce_epi4(
    const float* __restrict__ part, long partStride, int S,
    float* __restrict__ C, const float* __restrict__ E,
    int Mv, int Nv, int ldc, long sC0, int ldE, int total) {
  int idx = blockIdx.x*256 + threadIdx.x;
  if (idx >= total) return;
  int n = idx % Nv;
  int m = (idx / Nv) % Mv;
  int b0 = idx / (Nv * Mv);
  long co = b0*sC0 + (long)m*ldc + n;
  float v = 0.f;
  for (int s = 0; s < S; ++s) v += part[(long)s*partStride + co];
  v += E[(long)m*ldE + n];
  C[co] = v;
}

// ------------------------------------------------------ fp32 -> bf16 convert
__global__ __launch_bounds__(256) void cvt2_bf16(const float* __restrict__ src,
                                                 short* __restrict__ dst, int n8,
                                                 long srcStride, long dstStride, int total8) {
  int i = blockIdx.x*256 + threadIdx.x;
  if (i >= total8) return;
  int l = i / n8, j = i % n8;
  const float* s = src + srcStride*l + (long)8*j;
  short* d = dst + dstStride*l + (long)8*j;
  float4 a = *(const float4*)s;
  float4 b = *(const float4*)(s + 4);
  short8 o;
  o[0]=f2bf(a.x); o[1]=f2bf(a.y); o[2]=f2bf(a.z); o[3]=f2bf(a.w);
  o[4]=f2bf(b.x); o[5]=f2bf(b.y); o[6]=f2bf(b.z); o[7]=f2bf(b.w);
  *(short8*)d = o;
}

static void cvtT(hipStream_t s, const float* src, short* dst, long nPerLayer,
                 long srcStride, long dstStride, int L) {
  int n8 = (int)(nPerLayer / 8);
  int total8 = n8 * L;
  cvt2_bf16<<<dim3((total8 + 255)/256), dim3(256), 0, s>>>(src, dst, n8, srcStride, dstStride, total8);
}

// ================================================================ skinny GEMV4
template<int EPI>
__global__ __launch_bounds__(256) void gemv4(const float* __restrict__ A,
                                             const float* __restrict__ B,
                                             float* __restrict__ C,
                                             const float* __restrict__ bias,
                                             int N, int K, int ldc) {
  int wave = threadIdx.x >> 6, lane = threadIdx.x & 63;
  int n = blockIdx.x * 4 + wave;
  if (n >= N) return;
  const float* Brow = B + (long)n * K;
  float acc0 = 0.f, acc1 = 0.f, acc2 = 0.f, acc3 = 0.f;
  for (int k = lane * 4; k < K; k += 256) {
    float4 b = *(const float4*)(Brow + k);
    float4 a0 = *(const float4*)(A + 0*K + k);
    float4 a1 = *(const float4*)(A + 1*K + k);
    float4 a2 = *(const float4*)(A + 2*K + k);
    float4 a3 = *(const float4*)(A + 3*K + k);
    acc0 += a0.x*b.x + a0.y*b.y + a0.z*b.z + a0.w*b.w;
    acc1 += a1.x*b.x + a1.y*b.y + a1.z*b.z + a1.w*b.w;
    acc2 += a2.x*b.x + a2.y*b.y + a2.z*b.z + a2.w*b.w;
    acc3 += a3.x*b.x + a3.y*b.y + a3.z*b.z + a3.w*b.w;
  }
#pragma unroll
  for (int off = 32; off; off >>= 1) {
    acc0 += __shfl_xor(acc0, off);
    acc1 += __shfl_xor(acc1, off);
    acc2 += __shfl_xor(acc2, off);
    acc3 += __shfl_xor(acc3, off);
  }
  if (lane == 0) {
    float bs = bias[n];
    float v[4] = {acc0 + bs, acc1 + bs, acc2 + bs, acc3 + bs};
#pragma unroll
    for (int m = 0; m < 4; ++m) {
      float x = v[m];
      if (EPI == 2) x = x / (1.f + expf(-x));
      C[(long)m * ldc + n] = x;
    }
  }
}

// ---------------------------------------------------------------- small kernels
__global__ void embed_text_cls(const float* __restrict__ Wtok, const int* __restrict__ toks,
                               const float* __restrict__ pos_text, const float* __restrict__ cls_tok,
                               float* __restrict__ x) {
  int idx = blockIdx.x*256 + threadIdx.x;           // over B*65*DIM
  int d = idx % kDim;
  int t = (idx / kDim) % (kText + 1);
  int b = idx / (kDim * (kText + 1));
  float v;
  if (t < kText) {
    int tok = toks[b*kText + t];
    v = Wtok[(long)d*kVocab + tok] + pos_text[(long)t*kDim + d];
  } else {
    v = cls_tok[d];
  }
  x[((long)b*kTok + t)*kDim + d] = v;
}

__global__ void extract_patches(const float* __restrict__ img, short* __restrict__ pat) {
  int idx = blockIdx.x*256 + threadIdx.x;           // B*256*768
  int k = idx % 768;
  int p = (idx/768) % kNp;
  int b = idx/(768*kNp);
  int c = k >> 8, py = (k >> 4) & 15, px = k & 15;
  int hp = p >> 4, wp = p & 15;
  pat[idx] = f2bf(img[(((long)(b*3 + c))*kImg + hp*16 + py)*kImg + wp*16 + px]);
}

__global__ void time_freqs(const int* __restrict__ ts, float* __restrict__ temb) {
  int b = blockIdx.x, i = threadIdx.x;              // 128 threads
  float f = expf(-9.210340371976184f * (float)i / 128.f);
  float a = (float)ts[b] * f;
  temb[b*kTdim + i] = cosf(a);
  temb[b*kTdim + 128 + i] = sinf(a);
}

__global__ void silu_kernel(const float* __restrict__ in, float* __restrict__ outp, int n) {
  int i = blockIdx.x*256 + threadIdx.x;
  if (i < n) { float x = in[i]; outp[i] = x / (1.f + expf(-x)); }
}

__device__ __forceinline__ float block_sum(float v) {
  __shared__ float sh[4];
  for (int off = 32; off; off >>= 1) v += __shfl_down(v, off);
  if ((threadIdx.x & 63) == 0) sh[threadIdx.x >> 6] = v;
  __syncthreads();
  float s = sh[0] + sh[1] + sh[2] + sh[3];
  __syncthreads();
  return s;
}

__global__ __launch_bounds__(256) void ln_mod_kernel(
    const float* __restrict__ x, const float* __restrict__ g, const float* __restrict__ be,
    const float* __restrict__ mod, int shOff, int scOff, short* __restrict__ outp) {
  int row = blockIdx.x;                 // b*321 + t
  int b = row / kTok;
  const float* xr = x + (long)row*kDim;
  float s = 0.f, s2 = 0.f;
  for (int i = threadIdx.x; i < kDim; i += 256) { float v = xr[i]; s += v; s2 += v*v; }
  s = block_sum(s); s2 = block_sum(s2);
  float m = s / kDim;
  float inv = rsqrtf(s2 / kDim - m*m + kEps);
  const float* mb = mod + (long)b*(6*kDim);
  for (int i = threadIdx.x; i < kDim; i += 256) {
    float xn = (xr[i] - m)*inv*g[i] + be[i];
    outp[(long)row*kDim + i] = f2bf(xn*(1.f + mb[scOff + i]) + mb[shOff + i]);
  }
}

// fused: x_new = x_old + gate * sum_s part ; then LN+mod -> bf16, and write x_new
__global__ __launch_bounds__(256) void ln_mod_red_kernel(
    const float* __restrict__ xin, const float* __restrict__ part, long pStride, int S,
    const float* __restrict__ gate, const float* __restrict__ g, const float* __restrict__ be,
    const float* __restrict__ mod, int shOff, int scOff,
    float* __restrict__ xout, short* __restrict__ outp) {
  int row = blockIdx.x;                 // b*321 + t
  int b = row / kTok;
  long base = (long)row*kDim;
  const float* gt = gate + (long)b*(6*kDim);
  float v[4];
  float s = 0.f, s2 = 0.f;
#pragma unroll
  for (int c = 0; c < 4; ++c) {
    int i = threadIdx.x + 256*c;
    float acc = 0.f;
    for (int sp = 0; sp < S; ++sp) acc += part[(long)sp*pStride + base + i];
    float xv = xin[base + i] + gt[i] * acc;
    v[c] = xv; s += xv; s2 += xv*xv;
  }
  s = block_sum(s); s2 = block_sum(s2);
  float m = s / kDim;
  float inv = rsqrtf(s2 / kDim - m*m + kEps);
  const float* mb = mod + (long)b*(6*kDim);
#pragma unroll
  for (int c = 0; c < 4; ++c) {
    int i = threadIdx.x + 256*c;
    xout[base + i] = v[c];
    float xn = (v[c] - m)*inv*g[i] + be[i];
    outp[base + i] = f2bf(xn*(1.f + mb[scOff + i]) + mb[shOff + i]);
  }
}

__global__ __launch_bounds__(256) void final_ln_kernel(
    const float* __restrict__ x, const float* __restrict__ g, const float* __restrict__ be,
    short* __restrict__ yn) {
  int row = blockIdx.x;                 // b*256 + p
  int b = row / kNp, p = row % kNp;
  const float* xr = x + ((long)(b*kTok + kText + 1 + p))*kDim;
  float s = 0.f, s2 = 0.f;
  for (int i = threadIdx.x; i < kDim; i += 256) { float v = xr[i]; s += v; s2 += v*v; }
  s = block_sum(s); s2 = block_sum(s2);
  float m = s / kDim;
  float inv = rsqrtf(s2 / kDim - m*m + kEps);
  for (int i = threadIdx.x; i < kDim; i += 256)
    yn[(long)row*kDim + i] = f2bf((xr[i] - m)*inv*g[i] + be[i]);
}

// fused MLP2-reduce + final LN (img rows only)
__global__ __launch_bounds__(256) void final_ln_red_kernel(
    const float* __restrict__ xin, const float* __restrict__ part, long pStride, int S,
    const float* __restrict__ gate, const float* __restrict__ g, const float* __restrict__ be,
    short* __restrict__ yn) {
  int row = blockIdx.x;                 // b*256 + p
  int b = row / kNp, p = row % kNp;
  long xb = ((long)(b*kTok + kText + 1 + p))*kDim;
  const float* gt = gate + (long)b*(6*kDim);
  float v[4];
  float s = 0.f, s2 = 0.f;
#pragma unroll
  for (int c = 0; c < 4; ++c) {
    int i = threadIdx.x + 256*c;
    float acc = 0.f;
    for (int sp = 0; sp < S; ++sp) acc += part[(long)sp*pStride + xb + i];
    float xv = xin[xb + i] + gt[i] * acc;
    v[c] = xv; s += xv; s2 += xv*xv;
  }
  s = block_sum(s); s2 = block_sum(s2);
  float m = s / kDim;
  float inv = rsqrtf(s2 / kDim - m*m + kEps);
#pragma unroll
  for (int c = 0; c < 4; ++c) {
    int i = threadIdx.x + 256*c;
    yn[(long)row*kDim + i] = f2bf((v[c] - m)*inv*g[i] + be[i]);
  }
}

// RoPE: read fused fp32 QKV [row][3072], write bf16 q,k [row][1024]
__global__ __launch_bounds__(256) void rope_bf16(const float* __restrict__ qkv,
                                                 short* __restrict__ qb,
                                                 short* __restrict__ kb) {
  int idx = blockIdx.x*256 + threadIdx.x;          // B*321*1024
  int d = idx & (kDim - 1);
  int r = idx >> 10;
  int n = r % kTok;
  int hd = d & 63;
  int j = hd & 31;
  float inv = expf(-9.210340371976184f * (float)j / 32.f);
  float ang = (float)n * inv;
  float c = cosf(ang), s = sinf(ang);
  const float* row = qkv + (long)r * (3*kDim);
  int base = d - hd;
  float qv = row[d], kv = row[kDim + d];
  float qr, kr;
  if (hd < 32) { qr = -row[base + 2*hd + 1];      kr = -row[kDim + base + 2*hd + 1]; }
  else         { qr =  row[base + 2*(hd - 32)];   kr =  row[kDim + base + 2*(hd - 32)]; }
  qb[idx] = f2bf(qv*c + qr*s);
  kb[idx] = f2bf(kv*c + kr*s);
}

// V slice of fused QKV -> vtb[b][h][d][tok(384 pad0)] via LDS-tiled transpose
__global__ __launch_bounds__(256) void vtrans_t(const float* __restrict__ qkv,
                                                short* __restrict__ vtb) {
  int tt = blockIdx.x;            // tok tile 0..5
  int bh = blockIdx.y;            // b*16 + h
  int b = bh >> 4, h = bh & 15;
  __shared__ float tile[64][65];
  int t = threadIdx.x;
#pragma unroll
  for (int i = 0; i < 16; ++i) {
    int idx = t + 256*i;
    int tok = idx >> 6, d = idx & 63;
    int gtok = tt*64 + tok;
    float v = 0.f;
    if (gtok < kTok) v = qkv[((long)(b*kTok + gtok))*(3*kDim) + 2*kDim + h*kHd + d];
    tile[tok][d] = v;
  }
  __syncthreads();
#pragma unroll
  for (int i = 0; i < 16; ++i) {
    int idx = t + 256*i;
    int d = idx >> 6, tok = idx & 63;
    vtb[((long)bh*kHd + d)*kScLd + tt*64 + tok] = f2bf(tile[tok][d]);
  }
}

// 4 rows per block; writes bf16 P with zero pad cols [321,384)
__global__ __launch_bounds__(256) void softmax_rows4(float* __restrict__ sc,
                                                     short* __restrict__ scb, int nRows) {
  int wid = threadIdx.x >> 6, t = threadIdx.x & 63;
  int row = blockIdx.x*4 + wid;
  if (row >= nRows) return;
  float* r = sc + (long)row*kScLd;
  int bh = row / kTok, ri = row % kTok;
  short* d = scb + (long)bh*kScRow*kScLd + (long)ri*kScLd;
  float mx = -1e30f;
  for (int i = t; i < kTok; i += 64) mx = fmaxf(mx, r[i]);
  for (int off = 32; off; off >>= 1) mx = fmaxf(mx, __shfl_xor(mx, off));
  float sum = 0.f;
  for (int i = t; i < kTok; i += 64) { float e = expf(r[i] - mx); r[i] = e; sum += e; }
  for (int off = 32; off; off >>= 1) sum += __shfl_xor(sum, off);
  float invs = 1.f / sum;
  for (int i = t; i < kScLd; i += 64)
    d[i] = (i < kTok) ? f2bf(r[i] * invs) : (short)0;
}

__global__ void unpatchify(const float* __restrict__ op, float* __restrict__ outp) {
  int idx = blockIdx.x*256 + threadIdx.x;           // B*3*256*256
  int w = idx & 255;
  int h = (idx >> 8) & 255;
  int c = (idx >> 16) % 3;
  int b = idx / (3 * kImg * kImg);
  int hp = h >> 4, py = h & 15, wp = w >> 4, px = w & 15;
  outp[idx] = op[((long)(b*kNp + hp*16 + wp))*768 + c*256 + py*16 + px];
}

// fused: final split-K reduce + bias + unpatchify, direct to output
__global__ void unpatchify_red(const float* __restrict__ part, long pStride, int S,
                               const float* __restrict__ bias, float* __restrict__ outp) {
  int idx = blockIdx.x*256 + threadIdx.x;           // B*3*256*256
  int w = idx & 255;
  int h = (idx >> 8) & 255;
  int c = (idx >> 16) % 3;
  int b = idx / (3 * kImg * kImg);
  int hp = h >> 4, py = h & 15, wp = w >> 4, px = w & 15;
  long co = ((long)(b*kNp + hp*16 + wp))*768 + c*256 + py*16 + px;
  float v = bias[c*256 + py*16 + px];
  for (int s = 0; s < S; ++s) v += part[(long)s*pStride + co];
  outp[idx] = v;
}

// ---------------------------------------------------------------- launch
extern "C" void kernel_launch(void* const* d_in, const int* in_sizes, int n_in,
                              void* d_out, int out_size, void* d_ws, size_t ws_size,
                              hipStream_t stream) {
  (void)in_sizes; (void)n_in; (void)out_size;
  const float* noisy    = (const float*)d_in[0];
  const int*   toks     = (const int*)d_in[1];
  const int*   tsteps   = (const int*)d_in[2];
  const float* W_tok    = (const float*)d_in[3];
  const float* pos_text = (const float*)d_in[4];
  const float* W_patch  = (const float*)d_in[5];
  const float* pos_img  = (const float*)d_in[6];
  const float* cls_tok  = (const float*)d_in[7];
  const float* W_t1     = (const float*)d_in[8];
  const float* b_t1     = (const float*)d_in[9];
  const float* W_t2     = (const float*)d_in[10];
  const float* b_t2     = (const float*)d_in[11];
  const float* ln1_g    = (const float*)d_in[12];
  const float* ln1_b    = (const float*)d_in[13];
  const float* Wq       = (const float*)d_in[14];
  const float* Wk       = (const float*)d_in[15];
  const float* Wv       = (const float*)d_in[16];
  const float* Wo       = (const float*)d_in[17];
  const float* ln2_g    = (const float*)d_in[18];
  const float* ln2_b    = (const float*)d_in[19];
  const float* Wm1      = (const float*)d_in[20];
  const float* Wm2      = (const float*)d_in[21];
  const float* Wada     = (const float*)d_in[22];
  const float* b_ada    = (const float*)d_in[23];
  const float* fn_g     = (const float*)d_in[24];
  const float* fn_b     = (const float*)d_in[25];
  const float* W_final  = (const float*)d_in[26];
  const float* b_final  = (const float*)d_in[27];
  float* out = (float*)d_out;

  float* ws = (float*)d_ws;
  auto alloc = [&](long nf) { float* r = ws; ws += nf; return r; };

  const long seqSz = (long)kBn * kTok * kDim;            // 1,314,816
  float* x    = alloc(seqSz);
  float* qkv  = alloc((long)kBn*kTok*3*kDim);
  float* sc   = alloc((long)kBn*kHeads*kTok*kScLd);      // fp32 scores [bh][321][384]
  short* xnb  = (short*)alloc(seqSz/2);
  short* qb   = (short*)alloc(seqSz/2);
  short* kb   = (short*)alloc(seqSz/2);
  short* ob   = (short*)alloc(seqSz/2);
  short* vtb  = (short*)alloc((long)kBn*kHeads*kHd*kScLd/2);     // [bh][64][384]
  short* scb  = (short*)alloc((long)kBn*kHeads*kScRow*kScLd/2);  // [bh][384][384]
  short* patb = (short*)alloc((long)kBn*kNp*768/2);
  short* ynb  = (short*)alloc((long)kBn*kNp*kDim/2);
  float* temb = alloc(kBn*kTdim);
  float* t1   = alloc(kBn*kDim);
  float* temb2= alloc(kBn*kDim);
  float* st   = alloc(kBn*kDim);
  float* mod  = alloc(2L*kBn*6*kDim);
  short* hb   = (short*)sc;       // MLP hidden aliases fp32 scores (dead by MLP1)
  float* outp = qkv;              // fallback final out aliases qkv

  // bf16 weight arena
  const long oPatch = 0;
  const long nPatch = (long)kDim*768;
  const long perLayer = 3L*kDim*kDim + (long)kDim*kDim + 2L*kMlp*kDim;
  const long oLayer = nPatch;
  const long oFinal = nPatch + 2*perLayer;
  const long nFinal = (long)768*kDim;
  short* wAr = (short*)alloc((nPatch + 2*perLayer + nFinal)/2);

  const long scrStride = seqSz;
  float* scr = alloc(4*scrStride);
  bool split_ok = ((char*)ws - (char*)d_ws) <= (long)ws_size;

  // --- weight conversions (bf16 arena)
  cvtT(stream, W_patch, wAr + oPatch, nPatch, 0, 0, 1);
  cvtT(stream, Wq,  wAr + oLayer + 0,               (long)kDim*kDim, (long)kDim*kDim, perLayer, 2);
  cvtT(stream, Wk,  wAr + oLayer + (long)kDim*kDim, (long)kDim*kDim, (long)kDim*kDim, perLayer, 2);
  cvtT(stream, Wv,  wAr + oLayer + 2L*kDim*kDim,    (long)kDim*kDim, (long)kDim*kDim, perLayer, 2);
  cvtT(stream, Wo,  wAr + oLayer + 3L*kDim*kDim,    (long)kDim*kDim, (long)kDim*kDim, perLayer, 2);
  cvtT(stream, Wm1, wAr + oLayer + 4L*kDim*kDim,    (long)kMlp*kDim, (long)kMlp*kDim, perLayer, 2);
  cvtT(stream, Wm2, wAr + oLayer + 4L*kDim*kDim + (long)kMlp*kDim,
       (long)kMlp*kDim, (long)kMlp*kDim, perLayer, 2);
  cvtT(stream, W_final, wAr + oFinal, nFinal, 0, 0, 1);

  // --- embeddings
  embed_text_cls<<<(kBn*(kText+1)*kDim)/256, 256, 0, stream>>>(W_tok, toks, pos_text, cls_tok, x);
  extract_patches<<<(kBn*kNp*768)/256, 256, 0, stream>>>(noisy, patb);
  {
    GemmM p = mkm(patb, wAr + oPatch, split_ok ? scr : (x + (kText+1)*kDim),
                  kNp, kDim, 768, 768, 768, kDim);
    p.sA0 = (long)kNp*768; p.sC0 = (long)kTok*kDim;
    if (split_ok) {
      p.nSplit = 3; p.splitLen = 256; p.partStride = scrStride;
      run_gl128_part(stream, p, kBn);
      int total = kBn*kNp*kDim;
      reduce_epi4<<<(total+255)/256, 256, 0, stream>>>(scr, scrStride, 3,
          x + (kText+1)*kDim, pos_img, kNp, kDim, kDim, (long)kTok*kDim, kDim, total);
    } else {
      p.E = pos_img; p.ldE = kDim;
      run_gl128(stream, 4, false, p, kBn);
    }
  }
  // --- time embedding + modulation (all upfront)
  time_freqs<<<kBn, 128, 0, stream>>>(tsteps, temb);
  gemv4<2><<<kDim/4, 256, 0, stream>>>(temb, W_t1, t1, b_t1, kDim, kTdim, kDim);
  gemv4<1><<<kDim/4, 256, 0, stream>>>(t1, W_t2, temb2, b_t2, kDim, kDim, kDim);
  silu_kernel<<<(kBn*kDim + 255)/256, 256, 0, stream>>>(temb2, st, kBn*kDim);
  for (int l = 0; l < 2; ++l)
    gemv4<1><<<(6*kDim)/4, 256, 0, stream>>>(st, Wada + (long)l*6*kDim*kDim,
                                             mod + (long)l*kBn*6*kDim,
                                             b_ada + (long)l*6*kDim, 6*kDim, kDim, 6*kDim);

  // first LN
  ln_mod_kernel<<<kBn*kTok, 256, 0, stream>>>(x, ln1_g, ln1_b, mod, 0, kDim, xnb);

  for (int l = 0; l < 2; ++l) {
    const short* wqkv_l = wAr + oLayer + (long)l*perLayer;
    const short* wo_l   = wqkv_l + 3L*kDim*kDim;
    const short* wm1_l  = wqkv_l + 4L*kDim*kDim;
    const short* wm2_l  = wm1_l + (long)kMlp*kDim;
    float* mod_l = mod + (long)l*kBn*6*kDim;

    { // fused QKV projection -> qkv fp32
      GemmM p = mkm(xnb, wqkv_l, qkv, kBn*kTok, 3*kDim, kDim, kDim, kDim, 3*kDim);
      run_gl128(stream, 0, false, p, 1);
    }
    rope_bf16<<<(int)(seqSz/256), 256, 0, stream>>>(qkv, qb, kb);
    vtrans_t<<<dim3(kScLd/64, kBn*kHeads), 256, 0, stream>>>(qkv, vtb);

    { // scores = 0.125 * q @ k^T per (b,h)
      GemmM p = mkm(qb, kb, sc, kTok, kTok, kHd, kDim, kDim, kScLd);
      p.sA0 = (long)kTok*kDim; p.sA1 = kHd;
      p.sB0 = (long)kTok*kDim; p.sB1 = kHd;
      p.sC0 = (long)kHeads*kTok*kScLd; p.sC1 = (long)kTok*kScLd;
      p.innerB = kHeads; p.alpha = 0.125f;
      run_gl(stream, 0, false, p, kBn*kHeads);
    }
    {
      int nRows = kBn*kHeads*kTok;
      softmax_rows4<<<(nRows+3)/4, 256, 0, stream>>>(sc, scb, nRows);
    }
    { // o = P @ V per (b,h), K=384 (zero-padded) -> fast glds kernel, bf16 out
      GemmM p = mkm(scb, vtb, (float*)ob, kTok, kHd, kScLd, kScLd, kScLd, kDim);
      p.sA0 = (long)kHeads*kScRow*kScLd; p.sA1 = (long)kScRow*kScLd;
      p.sB0 = (long)kHeads*kHd*kScLd;    p.sB1 = (long)kHd*kScLd;
      p.sC0 = (long)kTok*kDim;           p.sC1 = kHd;
      p.innerB = kHeads;
      run_gl(stream, 0, true, p, kBn*kHeads);
    }
    { // o @ Wo^T
      GemmM p = mkm(ob, wo_l, split_ok ? scr : x, kBn*kTok, kDim, kDim, kDim, kDim, kDim);
      if (split_ok) {
        p.nSplit = 4; p.splitLen = 256; p.partStride = scrStride;
        run_gl128_part(stream, p, 1);
        ln_mod_red_kernel<<<kBn*kTok, 256, 0, stream>>>(x, scr, scrStride, 4,
            mod_l + 2*kDim, ln2_g + l*kDim, ln2_b + l*kDim, mod_l, 3*kDim, 4*kDim, x, xnb);
      } else {
        p.E = mod_l + 2*kDim; p.ldE = 6*kDim; p.rowsPB = kTok;
        run_gl128(stream, 5, false, p, 1);
        ln_mod_kernel<<<kBn*kTok, 256, 0, stream>>>(x, ln2_g + l*kDim, ln2_b + l*kDim,
                                                    mod_l, 3*kDim, 4*kDim, xnb);
      }
    }
    { // MLP1 + gelu, bf16 hidden
      GemmM p = mkm(xnb, wm1_l, (float*)hb, kBn*kTok, kMlp, kDim, kDim, kDim, kMlp);
      run_gl128(stream, 3, true, p, 1);
    }
    { // MLP2
      GemmM p = mkm(hb, wm2_l, split_ok ? scr : x, kBn*kTok, kDim, kMlp, kMlp, kMlp, kDim);
      if (split_ok) {
        p.nSplit = 4; p.splitLen = 1024; p.partStride = scrStride;
        run_gl128_part(stream, p, 1);
        if (l == 0) {
          ln_mod_red_kernel<<<kBn*kTok, 256, 0, stream>>>(x, scr, scrStride, 4,
              mod_l + 5*kDim, ln1_g + kDim, ln1_b + kDim,
              mod + (long)kBn*6*kDim, 0, kDim, x, xnb);
        } else {
          final_ln_red_kernel<<<kBn*kNp, 256, 0, stream>>>(x, scr, scrStride, 4,
              mod_l + 5*kDim, fn_g, fn_b, ynb);
        }
      } else {
        p.E = mod_l + 5*kDim; p.ldE = 6*kDim; p.rowsPB = kTok;
        run_gl128(stream, 5, false, p, 1);
        if (l == 0)
          ln_mod_kernel<<<kBn*kTok, 256, 0, stream>>>(x, ln1_g + kDim, ln1_b + kDim,
                                                      mod + (long)kBn*6*kDim, 0, kDim, xnb);
        else
          final_ln_kernel<<<kBn*kNp, 256, 0, stream>>>(x, fn_g, fn_b, ynb);
      }
    }
  }

  { // final projection
    GemmM p = mkm(ynb, wAr + oFinal, split_ok ? scr : outp, kBn*kNp, 768, kDim, kDim, kDim, 768);
    if (split_ok) {
      p.nSplit = 4; p.splitLen = 256; p.partStride = (long)kBn*kNp*768;
      run_gl128_part(stream, p, 1);
      unpatchify_red<<<(kBn*3*kImg*kImg)/256, 256, 0, stream>>>(scr, (long)kBn*kNp*768, 4,
                                                                b_final, out);
    } else {
      p.E = b_final;
      run_gl128(stream, 1, false, p, 1);
      unpatchify<<<(kBn*3*kImg*kImg)/256, 256, 0, stream>>>(outp, out);
    }
  }
}

// Round 5
// 758.776 us; speedup vs baseline: 1.1510x; 1.0367x over previous
//
#include <hip/hip_runtime.h>
#include <math.h>

constexpr int kBn    = 4;
constexpr int kText  = 64;
constexpr int kImg   = 256;
constexpr int kDim   = 1024;
constexpr int kHeads = 16;
constexpr int kHd    = 64;
constexpr int kNp    = 256;    // patches
constexpr int kTok   = 321;    // 64 text + 1 cls + 256 img
constexpr int kVocab = 50000;
constexpr int kTdim  = 256;
constexpr int kMlp   = 4096;
constexpr int kVLd   = 384;    // V^T row stride (tok padded to 384, zeros)
constexpr int kMod   = 12288;  // mod row stride per batch: [b][l][6*kDim]
constexpr float kEps = 1e-5f;

typedef __attribute__((ext_vector_type(8))) short short8;
typedef __attribute__((ext_vector_type(4))) short short4v;
typedef __attribute__((ext_vector_type(4))) float f32x4;

// RNE float -> bf16 bits
__device__ __forceinline__ short f2bf(float x) {
  unsigned u = __builtin_bit_cast(unsigned, x);
  unsigned r = (u + 0x7FFFu + ((u >> 16) & 1u)) >> 16;
  return (short)r;
}

// async global->LDS, 16B per lane, dest = base + lane*16 (wave-uniform base)
__device__ __forceinline__ void glds16(const short* g, short* l) {
  __builtin_amdgcn_global_load_lds(
      (const __attribute__((address_space(1))) unsigned int*)g,
      (__attribute__((address_space(3))) unsigned int*)l, 16, 0, 0);
}

// =================================================================== MFMA GEMM
// C[m][n] = alpha * sum_k A[m][k] * B[n][k]   (A,B bf16, fp32 accum)
// EPI: 0 none | 1 +bias[n] | 3 gelu | 4 +E[m][n] | 5 gated residual | 6 unpatchify+bias
struct GemmM {
  const short* A; const short* B; float* C; const float* E;
  int M, N, K, lda, ldb, ldc;
  long sA0, sA1, sB0, sB1, sC0, sC1;
  int innerB, ldE, rowsPB;
  float alpha;
  int nSplit, splitLen;
  long partStride;
};

// ------------------- 64M x 128N tile, glds staging (K%64==0) ----------------
// 4 waves; each wave owns 64x32 (acc[4][2]).  LDS XOR-swizzled (T2 both-sides).
template<int EPI, bool PART, bool OUTBF>
__global__ __launch_bounds__(256) void gemm_gl_n128(GemmM p) {
  int bz = blockIdx.z;
  int split = 0;
  if (PART) { split = bz % p.nSplit; bz /= p.nSplit; }
  int b1 = bz % p.innerB, b0 = bz / p.innerB;
  const short* A = p.A + b0*p.sA0 + b1*p.sA1;
  const short* B = p.B + b0*p.sB0 + b1*p.sB1;
  long cbase = b0*p.sC0 + b1*p.sC1 + (PART ? (long)split * p.partStride : 0);
  const float* E = p.E;

  int kBeg = PART ? split * p.splitLen : 0;
  int kEnd = PART ? min(p.K, kBeg + p.splitLen) : p.K;

  __shared__ short As[2][64*64];    // 64 rows x 128B
  __shared__ short Bs[2][128*64];   // 128 rows x 128B

  int tid  = threadIdx.x;
  int lane = tid & 63, widx = tid >> 6;
  int quad = lane >> 4, ln = lane & 15;
  int n0 = blockIdx.x * 128, m0 = blockIdx.y * 64;

  int l3 = lane >> 3, l7 = lane & 7;
  int kofs = (l7 ^ l3) * 8;                       // pre-swizzled element offset
  const short* gA0 = A + (long)(m0 + 16*widx + l3) * p.lda + kofs;
  const short* gA1 = gA0 + (long)8 * p.lda;
  const short* gB0 = B + (long)(n0 + 32*widx + l3) * p.ldb + kofs;
  const long ldb8 = (long)8 * p.ldb;
  short* lA = &As[0][(2*widx)*512];
  short* lB = &Bs[0][(4*widx)*512];

  auto stage = [&](int buf, int k0) {
    int boA = buf * 4096, boB = buf * 8192;
    glds16(gA0 + k0, lA + boA);
    glds16(gA1 + k0, lA + 512 + boA);
    glds16(gB0 + k0,            lB + boB);
    glds16(gB0 + ldb8 + k0,     lB + 512 + boB);
    glds16(gB0 + 2*ldb8 + k0,   lB + 1024 + boB);
    glds16(gB0 + 3*ldb8 + k0,   lB + 1536 + boB);
  };

  f32x4 zero = {0.f, 0.f, 0.f, 0.f};
  f32x4 acc[4][2];
#pragma unroll
  for (int i = 0; i < 4; ++i) { acc[i][0] = zero; acc[i][1] = zero; }

  stage(0, kBeg);
  int buf = 0;
  for (int k0 = kBeg; k0 < kEnd; k0 += 64) {
    if (k0 + 64 < kEnd) stage(buf ^ 1, k0 + 64);
    __syncthreads();
    const char* Ab = (const char*)&As[buf][0];
    const char* Bb = (const char*)&Bs[buf][0];
#pragma unroll
    for (int ks = 0; ks < 2; ++ks) {
      int cb = ks*64 + quad*16;
      short8 a[4], b[2];
#pragma unroll
      for (int mi = 0; mi < 4; ++mi) {
        int r = mi*16 + ln;
        a[mi] = *(const short8*)(Ab + r*128 + (cb ^ ((r & 7) << 4)));
      }
#pragma unroll
      for (int ni = 0; ni < 2; ++ni) {
        int r = 32*widx + ni*16 + ln;
        b[ni] = *(const short8*)(Bb + r*128 + (cb ^ ((r & 7) << 4)));
      }
#pragma unroll
      for (int mi = 0; mi < 4; ++mi)
#pragma unroll
        for (int ni = 0; ni < 2; ++ni)
          acc[mi][ni] = __builtin_amdgcn_mfma_f32_16x16x32_bf16(a[mi], b[ni], acc[mi][ni], 0, 0, 0);
    }
    __syncthreads();
    buf ^= 1;
  }

  // C/D layout: col = lane&15, row = quad*4 + reg  [verified m89/m91]
#pragma unroll
  for (int mi = 0; mi < 4; ++mi)
#pragma unroll
    for (int ni = 0; ni < 2; ++ni)
#pragma unroll
      for (int reg = 0; reg < 4; ++reg) {
        int gm = m0 + mi*16 + quad*4 + reg;
        int gn = n0 + 32*widx + ni*16 + ln;
        if (gm >= p.M || gn >= p.N) continue;
        float v = acc[mi][ni][reg] * p.alpha;
        if (EPI == 6) {
          // fused bias + unpatchify store: C = out[B][3][256][256]
          int bb = gm >> 8, pp = gm & 255;
          int cc = gn >> 8, py = (gn >> 4) & 15, px = gn & 15;
          long oidx = (((long)(bb*3 + cc)*256) + (pp>>4)*16 + py)*256 + (pp&15)*16 + px;
          p.C[oidx] = v + E[gn];
          continue;
        }
        long co = cbase + (long)gm * p.ldc + gn;
        if (!PART) {
          if (EPI == 1) v += E[gn];
          else if (EPI == 3) v = 0.5f*v*(1.f + erff(v*0.70710678118654752f));
          else if (EPI == 4) v += E[(long)gm*p.ldE + gn];
          else if (EPI == 5) v = p.C[co] + E[(long)(gm / p.rowsPB)*p.ldE + gn] * v;
        }
        if (OUTBF) ((short*)p.C)[co] = f2bf(v);
        else       p.C[co] = v;
      }
}

static GemmM mkm(const short* A, const short* B, float* C,
                 int M, int N, int K, int lda, int ldb, int ldc) {
  GemmM p; p.A = A; p.B = B; p.C = C; p.E = nullptr;
  p.M = M; p.N = N; p.K = K; p.lda = lda; p.ldb = ldb; p.ldc = ldc;
  p.sA0 = p.sA1 = p.sB0 = p.sB1 = p.sC0 = p.sC1 = 0;
  p.innerB = 1; p.ldE = 0; p.rowsPB = 1; p.alpha = 1.f;
  p.nSplit = 1; p.splitLen = 0; p.partStride = 0;
  return p;
}

static void run_gl128(hipStream_t s, int epi, bool outbf, const GemmM& p, int nb) {
  dim3 g((p.N + 127)/128, (p.M + 63)/64, nb), b(256, 1, 1);
  if (outbf) {
    if (epi == 3) gemm_gl_n128<3,false,true><<<g,b,0,s>>>(p);
    else          gemm_gl_n128<0,false,true><<<g,b,0,s>>>(p);
    return;
  }
  switch (epi) {
    case 0: gemm_gl_n128<0,false,false><<<g,b,0,s>>>(p); break;
    case 1: gemm_gl_n128<1,false,false><<<g,b,0,s>>>(p); break;
    case 4: gemm_gl_n128<4,false,false><<<g,b,0,s>>>(p); break;
    case 5: gemm_gl_n128<5,false,false><<<g,b,0,s>>>(p); break;
    case 6: gemm_gl_n128<6,false,false><<<g,b,0,s>>>(p); break;
  }
}

static void run_gl128_part(hipStream_t s, const GemmM& p, int nb) {
  dim3 g((p.N + 127)/128, (p.M + 63)/64, nb * p.nSplit), b(256, 1, 1);
  gemm_gl_n128<0,true,false><<<g,b,0,s>>>(p);
}

// ====================================================== fused flash attention
// grid (6 q-tiles, 64 bh), 4 waves; wave w owns q-rows qt*64+w*16..+16.
// S^T = mfma(K,Q) per kv-tile -> lane holds a full q-row slice (col = ln).
// online softmax; P relayout via per-wave swizzled LDS; o^T = mfma(V^T, P).
__global__ __launch_bounds__(256) void attn_fused(
    const short* __restrict__ qb, const short* __restrict__ kb,
    const short* __restrict__ vtb, short* __restrict__ ob) {
  __shared__ short plds[4096];           // 4 waves x 16 rows x 64 bf16
  int qt = blockIdx.x, bh = blockIdx.y;
  int b = bh >> 4, h = bh & 15;
  int tid = threadIdx.x;
  int lane = tid & 63, w = tid >> 6;
  int quad = lane >> 4, ln = lane & 15;

  int gq = qt*64 + w*16 + ln;            // this lane's q-row (S^T column)
  int gqc = min(gq, kTok - 1);
  const short* qp = qb + ((long)(b*kTok + gqc))*kDim + h*kHd;
  short8 qf0 = *(const short8*)(qp + quad*8);
  short8 qf1 = *(const short8*)(qp + 32 + quad*8);

  const short* kbase = kb + (long)b*kTok*kDim + h*kHd;
  const short* vbase = vtb + (long)bh*kHd*kVLd;
  short* pl = &plds[w*1024];
  int key = (ln & 7) << 2;               // word-index XOR key (per row)

  f32x4 zero = {0.f, 0.f, 0.f, 0.f};
  f32x4 oacc[4];
#pragma unroll
  for (int i = 0; i < 4; ++i) oacc[i] = zero;
  float m_run = -3.0e38f, l_run = 0.f;

  for (int t = 0; t < 6; ++t) {
    // ---- S^T tile: rows = ktok (64), cols = qrow (16)
    f32x4 st[4];
#pragma unroll
    for (int nt = 0; nt < 4; ++nt) {
      const short* kp = kbase + ((long)min(t*64 + nt*16 + ln, kTok - 1))*kDim;
      short8 k0 = *(const short8*)(kp + quad*8);
      short8 k1 = *(const short8*)(kp + 32 + quad*8);
      f32x4 a = zero;
      a = __builtin_amdgcn_mfma_f32_16x16x32_bf16(k0, qf0, a, 0, 0, 0);
      a = __builtin_amdgcn_mfma_f32_16x16x32_bf16(k1, qf1, a, 0, 0, 0);
      st[nt] = a;
    }
    // scale + mask (ktok > 320 -> -inf'ish)
#pragma unroll
    for (int nt = 0; nt < 4; ++nt)
#pragma unroll
      for (int reg = 0; reg < 4; ++reg) {
        int gk = t*64 + nt*16 + quad*4 + reg;
        float s = st[nt][reg] * 0.125f;
        st[nt][reg] = (gk < kTok) ? s : -3.0e38f;
      }
    // row max over 64 ktok: local 16 + reduce over quads (lane bits 4,5)
    float rm = -3.0e38f;
#pragma unroll
    for (int nt = 0; nt < 4; ++nt)
#pragma unroll
      for (int reg = 0; reg < 4; ++reg) rm = fmaxf(rm, st[nt][reg]);
    rm = fmaxf(rm, __shfl_xor(rm, 16));
    rm = fmaxf(rm, __shfl_xor(rm, 32));
    float m_new = fmaxf(m_run, rm);
    float scal = expf(m_run - m_new);
    float rs = 0.f;
#pragma unroll
    for (int nt = 0; nt < 4; ++nt)
#pragma unroll
      for (int reg = 0; reg < 4; ++reg) {
        float pv = expf(st[nt][reg] - m_new);
        st[nt][reg] = pv; rs += pv;
      }
    rs += __shfl_xor(rs, 16);
    rs += __shfl_xor(rs, 32);
    l_run = l_run * scal + rs;
    m_run = m_new;
#pragma unroll
    for (int dt = 0; dt < 4; ++dt)
#pragma unroll
      for (int reg = 0; reg < 4; ++reg) oacc[dt][reg] *= scal;

    // ---- P -> LDS (row = qrow = ln, 64 bf16, XOR-swizzled words)
#pragma unroll
    for (int nt = 0; nt < 4; ++nt) {
      unsigned w0 = (unsigned)(unsigned short)f2bf(st[nt][0])
                  | ((unsigned)(unsigned short)f2bf(st[nt][1]) << 16);
      unsigned w1 = (unsigned)(unsigned short)f2bf(st[nt][2])
                  | ((unsigned)(unsigned short)f2bf(st[nt][3]) << 16);
      int cs = (nt*8 + quad*2) ^ key;
      uint2 pk; pk.x = w0; pk.y = w1;
      *(uint2*)(pl + ln*64 + cs*2) = pk;
    }
    // B-fragments of P: lane reads its own row ln
    short8 pf0 = *(const short8*)(pl + ln*64 + (((0*16 + quad*4) ^ key))*2);
    short8 pf1 = *(const short8*)(pl + ln*64 + (((1*16 + quad*4) ^ key))*2);

    // ---- o^T += V^T . P^T
#pragma unroll
    for (int dt = 0; dt < 4; ++dt) {
      const short* vp = vbase + ((long)(dt*16 + ln))*kVLd + t*64;
      short8 v0 = *(const short8*)(vp + quad*8);
      short8 v1 = *(const short8*)(vp + 32 + quad*8);
      oacc[dt] = __builtin_amdgcn_mfma_f32_16x16x32_bf16(v0, pf0, oacc[dt], 0, 0, 0);
      oacc[dt] = __builtin_amdgcn_mfma_f32_16x16x32_bf16(v1, pf1, oacc[dt], 0, 0, 0);
    }
  }

  if (gq < kTok) {
    float invl = 1.f / l_run;
    short* op = ob + ((long)(b*kTok + gq))*kDim + h*kHd;
#pragma unroll
    for (int dt = 0; dt < 4; ++dt) {
      short4v o4;
#pragma unroll
      for (int reg = 0; reg < 4; ++reg) o4[reg] = f2bf(oacc[dt][reg] * invl);
      *(short4v*)(op + dt*16 + quad*4) = o4;
    }
  }
}

// ================================================== fp32 -> bf16 convert (all)
struct CvtJobs {
  const float* src[14];
  long dstOff[14];
  long start[14];      // start group index (8 elems per group)
};
__global__ __launch_bounds__(256) void cvt_all(CvtJobs j, short* __restrict__ dst, int totalG) {
  int g = blockIdx.x*256 + threadIdx.x;
  if (g >= totalG) return;
  int jo = 0;
#pragma unroll
  for (int i = 1; i < 14; ++i) if (g >= j.start[i]) jo = i;
  long lg = g - j.start[jo];
  const float* s = j.src[jo] + lg*8;
  short* d = dst + j.dstOff[jo] + lg*8;
  float4 a = *(const float4*)s;
  float4 b = *(const float4*)(s + 4);
  short8 o;
  o[0]=f2bf(a.x); o[1]=f2bf(a.y); o[2]=f2bf(a.z); o[3]=f2bf(a.w);
  o[4]=f2bf(b.x); o[5]=f2bf(b.y); o[6]=f2bf(b.z); o[7]=f2bf(b.w);
  *(short8*)d = o;
}

// ================================================================ skinny GEMV4
template<int EPI>   // 1: +bias | 2: silu(+bias)
__global__ __launch_bounds__(256) void gemv4(const float* __restrict__ A,
                                             const float* __restrict__ B,
                                             float* __restrict__ C,
                                             const float* __restrict__ bias,
                                             int N, int K, int ldc) {
  int wave = threadIdx.x >> 6, lane = threadIdx.x & 63;
  int n = blockIdx.x * 4 + wave;
  if (n >= N) return;
  const float* Brow = B + (long)n * K;
  float acc0 = 0.f, acc1 = 0.f, acc2 = 0.f, acc3 = 0.f;
  for (int k = lane * 4; k < K; k += 256) {
    float4 b = *(const float4*)(Brow + k);
    float4 a0 = *(const float4*)(A + 0*K + k);
    float4 a1 = *(const float4*)(A + 1*K + k);
    float4 a2 = *(const float4*)(A + 2*K + k);
    float4 a3 = *(const float4*)(A + 3*K + k);
    acc0 += a0.x*b.x + a0.y*b.y + a0.z*b.z + a0.w*b.w;
    acc1 += a1.x*b.x + a1.y*b.y + a1.z*b.z + a1.w*b.w;
    acc2 += a2.x*b.x + a2.y*b.y + a2.z*b.z + a2.w*b.w;
    acc3 += a3.x*b.x + a3.y*b.y + a3.z*b.z + a3.w*b.w;
  }
#pragma unroll
  for (int off = 32; off; off >>= 1) {
    acc0 += __shfl_xor(acc0, off);
    acc1 += __shfl_xor(acc1, off);
    acc2 += __shfl_xor(acc2, off);
    acc3 += __shfl_xor(acc3, off);
  }
  if (lane == 0) {
    float bs = bias[n];
    float v[4] = {acc0 + bs, acc1 + bs, acc2 + bs, acc3 + bs};
#pragma unroll
    for (int m = 0; m < 4; ++m) {
      float x = v[m];
      if (EPI == 2) x = x / (1.f + expf(-x));
      C[(long)m * ldc + n] = x;
    }
  }
}

// ---------------------------------------------------------------- small kernels
constexpr int kEmbBlocks = (kBn*(kText+1)*kDim)/256;     // 1040
__global__ void embed_patches(const float* __restrict__ Wtok, const int* __restrict__ toks,
                              const float* __restrict__ pos_text, const float* __restrict__ cls_tok,
                              float* __restrict__ x,
                              const float* __restrict__ img, short* __restrict__ pat) {
  int blk = blockIdx.x;
  if (blk < kEmbBlocks) {
    int idx = blk*256 + threadIdx.x;                     // B*65*DIM
    int d = idx % kDim;
    int t = (idx / kDim) % (kText + 1);
    int b = idx / (kDim * (kText + 1));
    float v;
    if (t < kText) {
      int tok = toks[b*kText + t];
      v = Wtok[(long)d*kVocab + tok] + pos_text[(long)t*kDim + d];
    } else {
      v = cls_tok[d];
    }
    x[((long)b*kTok + t)*kDim + d] = v;
  } else {
    int idx = (blk - kEmbBlocks)*256 + threadIdx.x;      // B*256*768
    int k = idx % 768;
    int p = (idx/768) % kNp;
    int b = idx/(768*kNp);
    int c = k >> 8, py = (k >> 4) & 15, px = k & 15;
    int hp = p >> 4, wp = p & 15;
    pat[idx] = f2bf(img[(((long)(b*3 + c))*kImg + hp*16 + py)*kImg + wp*16 + px]);
  }
}

__global__ void time_freqs(const int* __restrict__ ts, float* __restrict__ temb) {
  int b = blockIdx.x, i = threadIdx.x;                   // 128 threads
  float f = expf(-9.210340371976184f * (float)i / 128.f);
  float a = (float)ts[b] * f;
  temb[b*kTdim + i] = cosf(a);
  temb[b*kTdim + 128 + i] = sinf(a);
}

__device__ __forceinline__ float block_sum(float v) {
  __shared__ float sh[4];
  for (int off = 32; off; off >>= 1) v += __shfl_down(v, off);
  if ((threadIdx.x & 63) == 0) sh[threadIdx.x >> 6] = v;
  __syncthreads();
  float s = sh[0] + sh[1] + sh[2] + sh[3];
  __syncthreads();
  return s;
}

__global__ __launch_bounds__(256) void ln_mod_kernel(
    const float* __restrict__ x, const float* __restrict__ g, const float* __restrict__ be,
    const float* __restrict__ mod, int shOff, int scOff, int mStride,
    short* __restrict__ outp) {
  int row = blockIdx.x;                 // b*321 + t
  int b = row / kTok;
  const float* xr = x + (long)row*kDim;
  float s = 0.f, s2 = 0.f;
  for (int i = threadIdx.x; i < kDim; i += 256) { float v = xr[i]; s += v; s2 += v*v; }
  s = block_sum(s); s2 = block_sum(s2);
  float m = s / kDim;
  float inv = rsqrtf(s2 / kDim - m*m + kEps);
  const float* mb = mod + (long)b*mStride;
  for (int i = threadIdx.x; i < kDim; i += 256) {
    float xn = (xr[i] - m)*inv*g[i] + be[i];
    outp[(long)row*kDim + i] = f2bf(xn*(1.f + mb[scOff + i]) + mb[shOff + i]);
  }
}

// fused: x_new = x_old + gate * sum_s part ; then LN+mod -> bf16, write x_new
__global__ __launch_bounds__(256) void ln_mod_red_kernel(
    const float* __restrict__ xin, const float* __restrict__ part, long pStride, int S,
    const float* __restrict__ gate, const float* __restrict__ g, const float* __restrict__ be,
    const float* __restrict__ mod, int shOff, int scOff, int mStride,
    float* __restrict__ xout, short* __restrict__ outp) {
  int row = blockIdx.x;                 // b*321 + t
  int b = row / kTok;
  long base = (long)row*kDim;
  const float* gt = gate + (long)b*mStride;
  float v[4];
  float s = 0.f, s2 = 0.f;
#pragma unroll
  for (int c = 0; c < 4; ++c) {
    int i = threadIdx.x + 256*c;
    float acc = 0.f;
    for (int sp = 0; sp < S; ++sp) acc += part[(long)sp*pStride + base + i];
    float xv = xin[base + i] + gt[i] * acc;
    v[c] = xv; s += xv; s2 += xv*xv;
  }
  s = block_sum(s); s2 = block_sum(s2);
  float m = s / kDim;
  float inv = rsqrtf(s2 / kDim - m*m + kEps);
  const float* mb = mod + (long)b*mStride;
#pragma unroll
  for (int c = 0; c < 4; ++c) {
    int i = threadIdx.x + 256*c;
    xout[base + i] = v[c];
    float xn = (v[c] - m)*inv*g[i] + be[i];
    outp[base + i] = f2bf(xn*(1.f + mb[scOff + i]) + mb[shOff + i]);
  }
}

__global__ __launch_bounds__(256) void final_ln_kernel(
    const float* __restrict__ x, const float* __restrict__ g, const float* __restrict__ be,
    short* __restrict__ yn) {
  int row = blockIdx.x;                 // b*256 + p
  int b = row / kNp, p = row % kNp;
  const float* xr = x + ((long)(b*kTok + kText + 1 + p))*kDim;
  float s = 0.f, s2 = 0.f;
  for (int i = threadIdx.x; i < kDim; i += 256) { float v = xr[i]; s += v; s2 += v*v; }
  s = block_sum(s); s2 = block_sum(s2);
  float m = s / kDim;
  float inv = rsqrtf(s2 / kDim - m*m + kEps);
  for (int i = threadIdx.x; i < kDim; i += 256)
    yn[(long)row*kDim + i] = f2bf((xr[i] - m)*inv*g[i] + be[i]);
}

// fused MLP2-reduce + gated residual + final LN (img rows only)
__global__ __launch_bounds__(256) void final_ln_red_kernel(
    const float* __restrict__ xin, const float* __restrict__ part, long pStride, int S,
    const float* __restrict__ gate, const float* __restrict__ g, const float* __restrict__ be,
    int mStride, short* __restrict__ yn) {
  int row = blockIdx.x;                 // b*256 + p
  int b = row / kNp, p = row % kNp;
  long xb = ((long)(b*kTok + kText + 1 + p))*kDim;
  const float* gt = gate + (long)b*mStride;
  float v[4];
  float s = 0.f, s2 = 0.f;
#pragma unroll
  for (int c = 0; c < 4; ++c) {
    int i = threadIdx.x + 256*c;
    float acc = 0.f;
    for (int sp = 0; sp < S; ++sp) acc += part[(long)sp*pStride + xb + i];
    float xv = xin[xb + i] + gt[i] * acc;
    v[c] = xv; s += xv; s2 += xv*xv;
  }
  s = block_sum(s); s2 = block_sum(s2);
  float m = s / kDim;
  float inv = rsqrtf(s2 / kDim - m*m + kEps);
#pragma unroll
  for (int c = 0; c < 4; ++c) {
    int i = threadIdx.x + 256*c;
    yn[(long)row*kDim + i] = f2bf((v[c] - m)*inv*g[i] + be[i]);
  }
}

// RoPE (q,k -> bf16) + V^T transpose, merged (both read fused fp32 QKV)
constexpr int kRopeBlocks = (kBn*kTok*kDim)/256;         // 5136
__global__ __launch_bounds__(256) void rope_vtrans(const float* __restrict__ qkv,
                                                   short* __restrict__ qb,
                                                   short* __restrict__ kb,
                                                   short* __restrict__ vtb) {
  __shared__ float tile[64][65];
  int blk = blockIdx.x;
  if (blk < kRopeBlocks) {
    int idx = blk*256 + threadIdx.x;                     // B*321*1024
    int d = idx & (kDim - 1);
    int r = idx >> 10;
    int n = r % kTok;
    int hd = d & 63;
    int j = hd & 31;
    float inv = expf(-9.210340371976184f * (float)j / 32.f);
    float ang = (float)n * inv;
    float c = cosf(ang), s = sinf(ang);
    const float* row = qkv + (long)r * (3*kDim);
    int base = d - hd;
    float qv = row[d], kv = row[kDim + d];
    float qr, kr;
    if (hd < 32) { qr = -row[base + 2*hd + 1];      kr = -row[kDim + base + 2*hd + 1]; }
    else         { qr =  row[base + 2*(hd - 32)];   kr =  row[kDim + base + 2*(hd - 32)]; }
    qb[idx] = f2bf(qv*c + qr*s);
    kb[idx] = f2bf(kv*c + kr*s);
  } else {
    int r = blk - kRopeBlocks;                           // 6*64 blocks
    int tt = r % (kVLd/64);
    int bh = r / (kVLd/64);
    int b = bh >> 4, h = bh & 15;
    int t = threadIdx.x;
#pragma unroll
    for (int i = 0; i < 16; ++i) {
      int idx = t + 256*i;
      int tok = idx >> 6, d = idx & 63;
      int gtok = tt*64 + tok;
      float v = 0.f;
      if (gtok < kTok) v = qkv[((long)(b*kTok + gtok))*(3*kDim) + 2*kDim + h*kHd + d];
      tile[tok][d] = v;
    }
    __syncthreads();
#pragma unroll
    for (int i = 0; i < 16; ++i) {
      int idx = t + 256*i;
      int d = idx >> 6, tok = idx & 63;
      vtb[((long)bh*kHd + d)*kVLd + tt*64 + tok] = f2bf(tile[tok][d]);
    }
  }
}

// ---------------------------------------------------------------- launch
extern "C" void kernel_launch(void* const* d_in, const int* in_sizes, int n_in,
                              void* d_out, int out_size, void* d_ws, size_t ws_size,
                              hipStream_t stream) {
  (void)in_sizes; (void)n_in; (void)out_size;
  const float* noisy    = (const float*)d_in[0];
  const int*   toks     = (const int*)d_in[1];
  const int*   tsteps   = (const int*)d_in[2];
  const float* W_tok    = (const float*)d_in[3];
  const float* pos_text = (const float*)d_in[4];
  const float* W_patch  = (const float*)d_in[5];
  const float* pos_img  = (const float*)d_in[6];
  const float* cls_tok  = (const float*)d_in[7];
  const float* W_t1     = (const float*)d_in[8];
  const float* b_t1     = (const float*)d_in[9];
  const float* W_t2     = (const float*)d_in[10];
  const float* b_t2     = (const float*)d_in[11];
  const float* ln1_g    = (const float*)d_in[12];
  const float* ln1_b    = (const float*)d_in[13];
  const float* Wq       = (const float*)d_in[14];
  const float* Wk       = (const float*)d_in[15];
  const float* Wv       = (const float*)d_in[16];
  const float* Wo       = (const float*)d_in[17];
  const float* ln2_g    = (const float*)d_in[18];
  const float* ln2_b    = (const float*)d_in[19];
  const float* Wm1      = (const float*)d_in[20];
  const float* Wm2      = (const float*)d_in[21];
  const float* Wada     = (const float*)d_in[22];
  const float* b_ada    = (const float*)d_in[23];
  const float* fn_g     = (const float*)d_in[24];
  const float* fn_b     = (const float*)d_in[25];
  const float* W_final  = (const float*)d_in[26];
  const float* b_final  = (const float*)d_in[27];
  float* out = (float*)d_out;

  float* ws = (float*)d_ws;
  auto alloc = [&](long nf) { float* r = ws; ws += nf; return r; };

  const long seqSz = (long)kBn * kTok * kDim;            // 1,314,816
  float* x    = alloc(seqSz);
  float* qkv  = alloc((long)kBn*kTok*3*kDim);
  short* xnb  = (short*)alloc(seqSz/2);
  short* qb   = (short*)alloc(seqSz/2);
  short* kb   = (short*)alloc(seqSz/2);
  short* ob   = (short*)alloc(seqSz/2);
  short* vtb  = (short*)alloc((long)kBn*kHeads*kHd*kVLd/2);
  short* hb   = (short*)alloc((long)kBn*kTok*kMlp/2);    // MLP hidden bf16
  short* patb = (short*)alloc((long)kBn*kNp*768/2);
  short* ynb  = (short*)alloc((long)kBn*kNp*kDim/2);
  float* temb = alloc(kBn*kTdim);
  float* t1   = alloc(kBn*kDim);
  float* st   = alloc(kBn*kDim);
  float* modC = alloc((long)kBn*kMod);                   // [b][l][6*kDim]

  // bf16 weight arena
  const long nPatch = (long)kDim*768;
  const long perLayer = 4L*kDim*kDim + 2L*kMlp*kDim;     // q,k,v,o,m1,m2
  const long oLayer = nPatch;
  const long oFinal = nPatch + 2*perLayer;
  const long nFinal = (long)768*kDim;
  short* wAr = (short*)alloc((nPatch + 2*perLayer + nFinal)/2);

  const long scrStride = seqSz;
  float* scr = alloc(4*scrStride);
  bool split_ok = ((char*)ws - (char*)d_ws) <= (long)ws_size;

  // --- single weight-conversion dispatch
  {
    CvtJobs cj;
    int ji = 0; long cum = 0;
    auto addJob = [&](const float* s, long off, long n) {
      cj.src[ji] = s; cj.dstOff[ji] = off; cj.start[ji] = cum; cum += n/8; ++ji;
    };
    addJob(W_patch, 0, nPatch);
    for (int l = 0; l < 2; ++l) {
      long base = oLayer + (long)l*perLayer;
      addJob(Wq  + (long)l*kDim*kDim, base + 0,             (long)kDim*kDim);
      addJob(Wk  + (long)l*kDim*kDim, base + 1L*kDim*kDim,  (long)kDim*kDim);
      addJob(Wv  + (long)l*kDim*kDim, base + 2L*kDim*kDim,  (long)kDim*kDim);
      addJob(Wo  + (long)l*kDim*kDim, base + 3L*kDim*kDim,  (long)kDim*kDim);
      addJob(Wm1 + (long)l*kMlp*kDim, base + 4L*kDim*kDim,  (long)kMlp*kDim);
      addJob(Wm2 + (long)l*kMlp*kDim, base + 4L*kDim*kDim + (long)kMlp*kDim, (long)kMlp*kDim);
    }
    addJob(W_final, oFinal, nFinal);
    int totalG = (int)cum;
    cvt_all<<<(totalG + 255)/256, 256, 0, stream>>>(cj, wAr, totalG);
  }

  // --- embeddings (text+cls | patches) in one dispatch
  embed_patches<<<kEmbBlocks + (kBn*kNp*768)/256, 256, 0, stream>>>(
      W_tok, toks, pos_text, cls_tok, x, noisy, patb);
  { // patch projection, epi4 (+pos_img), no split-K
    GemmM p = mkm(patb, wAr, x + (kText+1)*kDim, kNp, kDim, 768, 768, 768, kDim);
    p.sA0 = (long)kNp*768; p.sC0 = (long)kTok*kDim;
    p.E = pos_img; p.ldE = kDim;
    run_gl128(stream, 4, false, p, kBn);
  }
  // --- time embedding + modulation (4 dispatches)
  time_freqs<<<kBn, 128, 0, stream>>>(tsteps, temb);
  gemv4<2><<<kDim/4, 256, 0, stream>>>(temb, W_t1, t1, b_t1, kDim, kTdim, kDim);
  gemv4<2><<<kDim/4, 256, 0, stream>>>(t1, W_t2, st, b_t2, kDim, kDim, kDim);  // st = silu(t_emb)
  gemv4<1><<<kMod/4, 256, 0, stream>>>(st, Wada, modC, b_ada, kMod, kDim, kMod);

  // first LN+mod
  ln_mod_kernel<<<kBn*kTok, 256, 0, stream>>>(x, ln1_g, ln1_b, modC, 0, kDim, kMod, xnb);

  for (int l = 0; l < 2; ++l) {
    const short* wqkv_l = wAr + oLayer + (long)l*perLayer;
    const short* wo_l   = wqkv_l + 3L*kDim*kDim;
    const short* wm1_l  = wqkv_l + 4L*kDim*kDim;
    const short* wm2_l  = wm1_l + (long)kMlp*kDim;
    const float* mod_l  = modC + (long)l*6*kDim;

    { // fused QKV projection -> qkv fp32
      GemmM p = mkm(xnb, wqkv_l, qkv, kBn*kTok, 3*kDim, kDim, kDim, kDim, 3*kDim);
      run_gl128(stream, 0, false, p, 1);
    }
    rope_vtrans<<<kRopeBlocks + (kVLd/64)*kBn*kHeads, 256, 0, stream>>>(qkv, qb, kb, vtb);

    // fused attention: scores + softmax + PV in one dispatch
    attn_fused<<<dim3(6, kBn*kHeads), 256, 0, stream>>>(qb, kb, vtb, ob);

    { // x += g_msa * (o @ Wo^T)  — epi5 direct, no split-K
      GemmM p = mkm(ob, wo_l, x, kBn*kTok, kDim, kDim, kDim, kDim, kDim);
      p.E = mod_l + 2*kDim; p.ldE = kMod; p.rowsPB = kTok;
      run_gl128(stream, 5, false, p, 1);
    }
    ln_mod_kernel<<<kBn*kTok, 256, 0, stream>>>(x, ln2_g + l*kDim, ln2_b + l*kDim,
                                                mod_l, 3*kDim, 4*kDim, kMod, xnb);
    { // MLP1 + gelu, bf16 hidden
      GemmM p = mkm(xnb, wm1_l, (float*)hb, kBn*kTok, kMlp, kDim, kDim, kDim, kMlp);
      run_gl128(stream, 3, true, p, 1);
    }
    { // MLP2 (split-K x4, K=4096) + fused reduce/residual/LN
      GemmM p = mkm(hb, wm2_l, split_ok ? scr : x, kBn*kTok, kDim, kMlp, kMlp, kMlp, kDim);
      if (split_ok) {
        p.nSplit = 4; p.splitLen = 1024; p.partStride = scrStride;
        run_gl128_part(stream, p, 1);
        if (l == 0) {
          ln_mod_red_kernel<<<kBn*kTok, 256, 0, stream>>>(x, scr, scrStride, 4,
              mod_l + 5*kDim, ln1_g + kDim, ln1_b + kDim,
              modC + 6*kDim, 0, kDim, kMod, x, xnb);
        } else {
          final_ln_red_kernel<<<kBn*kNp, 256, 0, stream>>>(x, scr, scrStride, 4,
              mod_l + 5*kDim, fn_g, fn_b, kMod, ynb);
        }
      } else {
        p.E = mod_l + 5*kDim; p.ldE = kMod; p.rowsPB = kTok;
        run_gl128(stream, 5, false, p, 1);
        if (l == 0)
          ln_mod_kernel<<<kBn*kTok, 256, 0, stream>>>(x, ln1_g + kDim, ln1_b + kDim,
                                                      modC + 6*kDim, 0, kDim, kMod, xnb);
        else
          final_ln_kernel<<<kBn*kNp, 256, 0, stream>>>(x, fn_g, fn_b, ynb);
      }
    }
  }

  { // final projection: epi6 = bias + unpatchify fused, direct to out
    GemmM p = mkm(ynb, wAr + oFinal, out, kBn*kNp, 768, kDim, kDim, kDim, 768);
    p.E = b_final;
    run_gl128(stream, 6, false, p, 1);
  }
}